// Round 1
// baseline (197.186 us; speedup 1.0000x reference)
//
#include <hip/hip_runtime.h>

#define EPSLN 1e-5f

__device__ __forceinline__ float wsum(float v){
  #pragma unroll
  for(int o=32;o;o>>=1) v += __shfl_xor(v,o);
  return v;
}
__device__ __forceinline__ float wmax(float v){
  #pragma unroll
  for(int o=32;o;o>>=1) v = fmaxf(v,__shfl_xor(v,o));
  return v;
}

// A: per (b,i,s) row stats: x_energy, mean|x|, sum p, sum p^2
__global__ void kA(const float* __restrict__ xin, const float* __restrict__ p,
                   float* __restrict__ xe, float* __restrict__ xa,
                   float* __restrict__ Sv, float* __restrict__ SSv){
  int row = blockIdx.x*4 + (threadIdx.x>>6);
  int lane = threadIdx.x & 63;
  float xv = xin[row*64+lane];
  float pv = p[row*64+lane];
  float s1 = wsum(xv);
  float s2 = wsum(fabsf(xv));
  float s3 = wsum(pv);
  float s4 = wsum(pv*pv);
  if(lane==0){ xe[row]=s1*(1.f/64.f); xa[row]=s2*(1.f/64.f); Sv[row]=s3; SSv[row]=s4; }
}

// B: per (b,i): x_norm (max over s), spline basis (4 nonzero coeffs), er2[b,i,j,s]
__global__ void kB(const float* __restrict__ xe, const float* __restrict__ sw,
                   const float* __restrict__ bs, const float* __restrict__ om,
                   float* __restrict__ er2){
  int bi = blockIdx.x;           // (b*16+i)
  int i = bi & 15;
  int tid = threadIdx.x;         // = s
  __shared__ float swL[16*67];
  __shared__ float bsL[16], omL[16];
  __shared__ float red[4];
  for(int k=tid;k<16*67;k+=256) swL[k] = sw[i*16*67 + k];
  if(tid<16){ bsL[tid]=bs[i*16+tid]; omL[tid]=fabsf(om[i*16+tid]); }
  float v = xe[bi*256+tid];
  float m = wmax(fabsf(v));
  if((tid&63)==0) red[tid>>6]=m;
  __syncthreads();
  m = fmaxf(fmaxf(red[0],red[1]),fmaxf(red[2],red[3]));
  float xn = v/(m+1e-8f);
  xn = fminf(fmaxf(xn,-0.99f),0.99f);
  float sil = xn/(1.f+expf(-xn));
  float vv = (xn+1.f)*33.f;          // (x - grid_c)/h = vv - c
  int c0 = (int)floorf(vv)-1;
  float acc[16];
  #pragma unroll
  for(int j=0;j<16;j++) acc[j]=0.f;
  #pragma unroll
  for(int k=0;k<4;k++){
    int c = c0+k;
    if(c<0||c>66) continue;
    float d = fabsf(vv-(float)c);
    float bas = d<1.f ? (2.f/3.f - d*d + d*d*d*0.5f)
              : (d<2.f ? (2.f-d)*(2.f-d)*(2.f-d)*(1.f/6.f) : 0.f);
    #pragma unroll
    for(int j=0;j<16;j++) acc[j] += bas*swL[j*67+c];
  }
  #pragma unroll
  for(int j=0;j<16;j++){
    er2[(bi*16+j)*256+tid] = sil*bsL[j] + acc[j] + omL[j];
  }
}

// C1: edge_energies[b,i,j] = mean_s |er2|*xabs
__global__ void kC1(const float* __restrict__ er2, const float* __restrict__ xa,
                    float* __restrict__ ee){
  int r = blockIdx.x*4 + (threadIdx.x>>6); // (b*16+i)*16+j
  int lane = threadIdx.x&63;
  int bi = r>>4;
  float sum=0.f;
  #pragma unroll
  for(int k=0;k<4;k++){
    int s = lane + k*64;
    sum += fabsf(er2[r*256+s])*xa[bi*256+s];
  }
  sum = wsum(sum);
  if(lane==0) ee[r] = sum*(1.f/256.f);
}

// C2: mask, coefficient c = mult*mask
__global__ void kC2(const float* __restrict__ ee, const float* __restrict__ tau,
                    const float* __restrict__ temp, float* __restrict__ mask,
                    float* __restrict__ cc){
  int g = blockIdx.x*256+threadIdx.x; // 2048 = b*(i*16+j)
  if(g>=2048) return;
  int ij = g & 255;
  float tv = fabsf(temp[0])+1e-4f;
  float ta = fabsf(tau[ij]);
  float e = ee[g];
  float mk = 1.f/(1.f+expf(-(e-ta)/tv));
  mask[g]=mk;
  cc[g]= e/(ta+1e-8f)*mk;
}

// E1: LN stats of K,Q rows from S,SS closed form
__global__ void kE1(const float* __restrict__ Sv, const float* __restrict__ SSv,
                    const float* __restrict__ cc,
                    float* __restrict__ muK, float* __restrict__ rK,
                    float* __restrict__ muQ, float* __restrict__ rQ){
  int bj = blockIdx.x;  // b*16+j
  int b = bj>>4, j = bj&15;
  int s = threadIdx.x;
  float sk=0,ssk=0,sq=0,ssq=0;
  #pragma unroll
  for(int m=0;m<8;m++){
    float ck = cc[(b*16+m)*16+j];
    float cq = cc[(b*16+m+8)*16+j];
    sk  += ck*Sv[(b*16+m)*256+s];
    ssk += ck*ck*SSv[(b*16+m)*256+s];
    sq  += cq*Sv[(b*16+m+8)*256+s];
    ssq += cq*cq*SSv[(b*16+m+8)*256+s];
  }
  float mk = sk*(1.f/512.f);
  float vk = ssk*(1.f/512.f) - mk*mk;
  float mq = sq*(1.f/512.f);
  float vq = ssq*(1.f/512.f) - mq*mq;
  int o = bj*256+s;
  muK[o]=mk; rK[o]=rsqrtf(vk+EPSLN);
  muQ[o]=mq; rQ[o]=rsqrtf(vq+EPSLN);
}

// E2: gram G[b,m,s,t] = sum_d p[b,m,s,d]*p[b,m+8,t,d]; 32x32 tiles
__global__ void kE2(const float* __restrict__ p, float* __restrict__ G){
  int bm = blockIdx.z; int b = bm>>3, m = bm&7;
  int s0 = blockIdx.x*32, t0 = blockIdx.y*32;
  __shared__ float As[32][65], Bs2[32][65];
  int tid=threadIdx.x;
  const float* Ab = p + ((b*16+m)*256 + s0)*64;
  const float* Bb = p + ((b*16+m+8)*256 + t0)*64;
  for(int k=tid;k<2048;k+=256){ As[k>>6][k&63]=Ab[k]; Bs2[k>>6][k&63]=Bb[k]; }
  __syncthreads();
  int sl = tid>>5, tl = tid&31;
  #pragma unroll
  for(int q=0;q<4;q++){
    int sr = sl + q*8;
    float acc=0.f;
    #pragma unroll
    for(int d=0;d<64;d++) acc += As[sr][d]*Bs2[tl][d];
    G[(bm*256+s0+sr)*256 + t0+tl] = acc;
  }
}

// D: x = masked mean over i; LN (ln_w/ln_b); x' = xn@W2[j] + b_param
__global__ void kD(const float* __restrict__ xin, const float* __restrict__ er2,
                   const float* __restrict__ mask, const float* __restrict__ W2,
                   const float* __restrict__ lnw, const float* __restrict__ lnb,
                   const float* __restrict__ bp,
                   float* __restrict__ xout, float* __restrict__ xp){
  int st = blockIdx.x, j = blockIdx.y, b = blockIdx.z;
  int tid = threadIdx.x, w = tid>>6, lane = tid&63;
  __shared__ float W2L[4096];
  __shared__ float mcL[16];
  for(int k=tid;k<4096;k+=256) W2L[k]=W2[j*4096+k];
  if(tid<16) mcL[tid]=mask[(b*16+tid)*16+j];
  __syncthreads();
  float lw = lnw[j*64+lane], lb = lnb[j*64+lane];
  #pragma unroll
  for(int ri=0;ri<4;ri++){
    int s = st*16 + w*4 + ri;
    float acc=0.f;
    #pragma unroll
    for(int i=0;i<16;i++){
      acc += er2[((b*16+i)*16+j)*256+s]*mcL[i]*xin[((b*16+i)*256+s)*64+lane];
    }
    float xval = acc*(1.f/16.f);
    int rowo = ((b*16+j)*256+s)*64;
    xout[rowo+lane]=xval;
    float mu = wsum(xval)*(1.f/64.f);
    float dv = xval-mu;
    float var = wsum(dv*dv)*(1.f/64.f);
    float xnv = dv*rsqrtf(var+EPSLN)*lw + lb;
    float acc2 = bp[(j*256+s)*64+lane];
    #pragma unroll 8
    for(int f=0;f<64;f++){
      acc2 += __shfl(xnv,f)*W2L[f*64+lane];
    }
    xp[rowo+lane]=acc2;
  }
}

// F: raw = (sum_m a*G - 512 muK muQ)*rK*rQ*inv -> softmax -> AV + diag + conv + residuals
__global__ void __launch_bounds__(256) kF(
    const float* __restrict__ G, const float* __restrict__ cc,
    const float* __restrict__ muK, const float* __restrict__ rK,
    const float* __restrict__ muQ, const float* __restrict__ rQ,
    const float* __restrict__ xp, const float* __restrict__ cw,
    const float* __restrict__ xarr, const float* __restrict__ temp,
    const float* __restrict__ alpha, const float* __restrict__ beta,
    const float* __restrict__ gamma_, const float* __restrict__ theta,
    float* __restrict__ out){
  int st = blockIdx.x, j = blockIdx.y, b = blockIdx.z;
  int tid = threadIdx.x, w=tid>>6, lane=tid&63;
  __shared__ float probL[16*256];
  __shared__ float pare[4][16][64];
  __shared__ float red[4];
  float tv = fabsf(temp[0])+1e-4f;
  float inv = 1.f/(sqrtf(512.f)*tv);
  float aM[8];
  #pragma unroll
  for(int m=0;m<8;m++) aM[m]=cc[(b*16+m)*16+j]*cc[(b*16+m+8)*16+j];
  int bj = b*16+j;
  const float* Gb = G + (size_t)(b*8)*65536;
  float mQt = muQ[bj*256+tid];
  float rQt = rQ[bj*256+tid];
  for(int si=0;si<16;si++){
    int s = st*16+si;
    float mKs = muK[bj*256+s], rKs = rK[bj*256+s];
    float dot=0.f;
    #pragma unroll
    for(int m=0;m<8;m++) dot += aM[m]*Gb[m*65536 + s*256 + tid];
    float raw = (dot - 512.f*mKs*mQt)*rKs*rQt*inv;
    __syncthreads();                 // red reads of prev iter done
    float mx0 = wmax(raw);
    if(lane==0) red[w]=mx0;
    __syncthreads();
    float mx = fmaxf(fmaxf(red[0],red[1]),fmaxf(red[2],red[3]));
    float ex = expf(raw-mx);
    float sm0 = wsum(ex);
    __syncthreads();                 // red max reads done
    if(lane==0) red[w]=sm0;
    __syncthreads();
    float sm = red[0]+red[1]+red[2]+red[3];
    probL[si*256+tid] = ex/sm;
  }
  __syncthreads();
  // AV: wave w covers t in [w*64, w*64+64); partials for all 16 rows
  float accs[16];
  #pragma unroll
  for(int k=0;k<16;k++) accs[k]=0.f;
  const float* xpb = xp + (size_t)bj*16384;
  for(int t=w*64; t<w*64+64; t++){
    float xv = xpb[t*64+lane];
    #pragma unroll
    for(int si2=0;si2<16;si2++) accs[si2] += probL[si2*256+t]*xv;
  }
  #pragma unroll
  for(int si2=0;si2<16;si2++) pare[w][si2][lane]=accs[si2];
  __syncthreads();
  float al = fabsf(alpha[j]), be=fabsf(beta[j]), th=fabsf(theta[j]), ga=gamma_[j];
  const float* wq = cw + (j*64+lane)*9;
  float w0=wq[0],w1=wq[1],w2=wq[2],w3v=wq[3],w4=wq[4],w5=wq[5],w6=wq[6],w7=wq[7],w8=wq[8];
  #pragma unroll
  for(int q=0;q<4;q++){
    int si2 = w*4+q;
    int s = st*16+si2;
    float gl = pare[0][si2][lane]+pare[1][si2][lane]+pare[2][si2][lane]+pare[3][si2][lane];
    // depthwise 3x3 conv on 16x16 view of s, channel = lane
    int r = s>>4, ci = s&15;
    float cv=0.f;
    #pragma unroll
    for(int dr=0;dr<3;dr++){
      int rr=r+dr-1;
      if(rr<0||rr>15) continue;
      float kw0 = dr==0?w0:(dr==1?w3v:w6);
      float kw1 = dr==0?w1:(dr==1?w4:w7);
      float kw2 = dr==0?w2:(dr==1?w5:w8);
      if(ci>0)  cv += xpb[(rr*16+ci-1)*64+lane]*kw0;
                cv += xpb[(rr*16+ci  )*64+lane]*kw1;
      if(ci<15) cv += xpb[(rr*16+ci+1)*64+lane]*kw2;
    }
    size_t gi = ((size_t)bj*256+s)*64+lane;
    float res = be*gl + al*xpb[s*64+lane] + th*cv + ga*xarr[gi];
    out[gi]=res;
  }
}

extern "C" void kernel_launch(void* const* d_in, const int* in_sizes, int n_in,
                              void* d_out, int out_size, void* d_ws, size_t ws_size,
                              hipStream_t stream) {
  const float* xin = (const float*)d_in[0];
  const float* pxp = (const float*)d_in[1];
  const float* sw  = (const float*)d_in[2];
  const float* bs  = (const float*)d_in[3];
  const float* tau = (const float*)d_in[4];
  const float* temp= (const float*)d_in[5];
  const float* om  = (const float*)d_in[6];
  const float* W2  = (const float*)d_in[7];
  const float* bp  = (const float*)d_in[8];
  const float* lnw = (const float*)d_in[9];
  const float* lnb = (const float*)d_in[10];
  const float* alpha=(const float*)d_in[11];
  const float* beta= (const float*)d_in[12];
  const float* gam = (const float*)d_in[13];
  const float* theta=(const float*)d_in[14];
  const float* cw  = (const float*)d_in[15];
  float* outp = (float*)d_out;
  float* xpo  = outp + 2097152;   // x_prime = second output

  float* ws  = (float*)d_ws;
  float* xe  = ws;                // 32768
  float* xa  = xe + 32768;        // 32768
  float* Sv  = xa + 32768;        // 32768
  float* SSv = Sv + 32768;        // 32768
  float* er2 = SSv + 32768;       // 524288
  float* ee  = er2 + 524288;      // 2048
  float* mask= ee + 2048;         // 2048
  float* ccv = mask + 2048;       // 2048
  float* muK = ccv + 2048;        // 32768
  float* rKv = muK + 32768;       // 32768
  float* muQ = rKv + 32768;       // 32768
  float* rQv = muQ + 32768;       // 32768
  float* Gv  = rQv + 32768;       // 4194304
  float* xv  = Gv + 4194304;      // 2097152

  kA<<<8192,256,0,stream>>>(xin,pxp,xe,xa,Sv,SSv);
  kB<<<128,256,0,stream>>>(xe,sw,bs,om,er2);
  kC1<<<512,256,0,stream>>>(er2,xa,ee);
  kC2<<<8,256,0,stream>>>(ee,tau,temp,mask,ccv);
  kE1<<<128,256,0,stream>>>(Sv,SSv,ccv,muK,rKv,muQ,rQv);
  kE2<<<dim3(8,8,64),256,0,stream>>>(pxp,Gv);
  kD<<<dim3(16,16,8),256,0,stream>>>(xin,er2,mask,W2,lnw,lnb,bp,xv,xpo);
  kF<<<dim3(16,16,8),256,0,stream>>>(Gv,ccv,muK,rKv,muQ,rQv,xpo,cw,xv,temp,
                                     alpha,beta,gam,theta,outp);
}

// Round 2
// 136.687 us; speedup vs baseline: 1.4426x; 1.4426x over previous
//
#include <hip/hip_runtime.h>

#define EPSLN 1e-5f

__device__ __forceinline__ float wsum(float v){
  #pragma unroll
  for(int o=32;o;o>>=1) v += __shfl_xor(v,o);
  return v;
}
__device__ __forceinline__ float wmax(float v){
  #pragma unroll
  for(int o=32;o;o>>=1) v = fmaxf(v,__shfl_xor(v,o));
  return v;
}

// A: per (b,i,s) row stats: x_energy, mean|x|, sum p, sum p^2
__global__ void kA(const float* __restrict__ xin, const float* __restrict__ p,
                   float* __restrict__ xe, float* __restrict__ xa,
                   float* __restrict__ Sv, float* __restrict__ SSv){
  int row = blockIdx.x*4 + (threadIdx.x>>6);
  int lane = threadIdx.x & 63;
  float xv = xin[row*64+lane];
  float pv = p[row*64+lane];
  float s1 = wsum(xv);
  float s2 = wsum(fabsf(xv));
  float s3 = wsum(pv);
  float s4 = wsum(pv*pv);
  if(lane==0){ xe[row]=s1*(1.f/64.f); xa[row]=s2*(1.f/64.f); Sv[row]=s3; SSv[row]=s4; }
}

// B: per (b,i): x_norm (max over s), spline basis (4 nonzero coeffs), er2[b,i,j,s]
__global__ void kB(const float* __restrict__ xe, const float* __restrict__ sw,
                   const float* __restrict__ bs, const float* __restrict__ om,
                   float* __restrict__ er2){
  int bi = blockIdx.x;           // (b*16+i)
  int i = bi & 15;
  int tid = threadIdx.x;         // = s
  __shared__ float swL[16*67];
  __shared__ float bsL[16], omL[16];
  __shared__ float red[4];
  for(int k=tid;k<16*67;k+=256) swL[k] = sw[i*16*67 + k];
  if(tid<16){ bsL[tid]=bs[i*16+tid]; omL[tid]=fabsf(om[i*16+tid]); }
  float v = xe[bi*256+tid];
  float m = wmax(fabsf(v));
  if((tid&63)==0) red[tid>>6]=m;
  __syncthreads();
  m = fmaxf(fmaxf(red[0],red[1]),fmaxf(red[2],red[3]));
  float xn = v/(m+1e-8f);
  xn = fminf(fmaxf(xn,-0.99f),0.99f);
  float sil = xn/(1.f+expf(-xn));
  float vv = (xn+1.f)*33.f;          // (x - grid_c)/h = vv - c
  int c0 = (int)floorf(vv)-1;
  float acc[16];
  #pragma unroll
  for(int j=0;j<16;j++) acc[j]=0.f;
  #pragma unroll
  for(int k=0;k<4;k++){
    int c = c0+k;
    if(c<0||c>66) continue;
    float d = fabsf(vv-(float)c);
    float bas = d<1.f ? (2.f/3.f - d*d + d*d*d*0.5f)
              : (d<2.f ? (2.f-d)*(2.f-d)*(2.f-d)*(1.f/6.f) : 0.f);
    #pragma unroll
    for(int j=0;j<16;j++) acc[j] += bas*swL[j*67+c];
  }
  #pragma unroll
  for(int j=0;j<16;j++){
    er2[(bi*16+j)*256+tid] = sil*bsL[j] + acc[j] + omL[j];
  }
}

// C1: edge_energies[b,i,j] = mean_s |er2|*xabs
__global__ void kC1(const float* __restrict__ er2, const float* __restrict__ xa,
                    float* __restrict__ ee){
  int r = blockIdx.x*4 + (threadIdx.x>>6); // (b*16+i)*16+j
  int lane = threadIdx.x&63;
  int bi = r>>4;
  float sum=0.f;
  #pragma unroll
  for(int k=0;k<4;k++){
    int s = lane + k*64;
    sum += fabsf(er2[r*256+s])*xa[bi*256+s];
  }
  sum = wsum(sum);
  if(lane==0) ee[r] = sum*(1.f/256.f);
}

// C2: mask, coefficient c = mult*mask
__global__ void kC2(const float* __restrict__ ee, const float* __restrict__ tau,
                    const float* __restrict__ temp, float* __restrict__ mask,
                    float* __restrict__ cc){
  int g = blockIdx.x*256+threadIdx.x; // 2048 = b*(i*16+j)
  if(g>=2048) return;
  int ij = g & 255;
  float tv = fabsf(temp[0])+1e-4f;
  float ta = fabsf(tau[ij]);
  float e = ee[g];
  float mk = 1.f/(1.f+expf(-(e-ta)/tv));
  mask[g]=mk;
  cc[g]= e/(ta+1e-8f)*mk;
}

// E1: LN stats of K,Q rows from S,SS closed form
__global__ void kE1(const float* __restrict__ Sv, const float* __restrict__ SSv,
                    const float* __restrict__ cc,
                    float* __restrict__ muK, float* __restrict__ rK,
                    float* __restrict__ muQ, float* __restrict__ rQ){
  int bj = blockIdx.x;  // b*16+j
  int b = bj>>4, j = bj&15;
  int s = threadIdx.x;
  float sk=0,ssk=0,sq=0,ssq=0;
  #pragma unroll
  for(int m=0;m<8;m++){
    float ck = cc[(b*16+m)*16+j];
    float cq = cc[(b*16+m+8)*16+j];
    sk  += ck*Sv[(b*16+m)*256+s];
    ssk += ck*ck*SSv[(b*16+m)*256+s];
    sq  += cq*Sv[(b*16+m+8)*256+s];
    ssq += cq*cq*SSv[(b*16+m+8)*256+s];
  }
  float mk = sk*(1.f/512.f);
  float vk = ssk*(1.f/512.f) - mk*mk;
  float mq = sq*(1.f/512.f);
  float vq = ssq*(1.f/512.f) - mq*mq;
  int o = bj*256+s;
  muK[o]=mk; rK[o]=rsqrtf(vk+EPSLN);
  muQ[o]=mq; rQ[o]=rsqrtf(vq+EPSLN);
}

// E2: gram G[b,m,s,t] = sum_d p[b,m,s,d]*p[b,m+8,t,d]
// 64x64 tile per block; wave w owns 16 rows x 64 cols (lane = col);
// A via uniform-address b128 broadcast, B lane-linear (conflict-free).
__global__ void __launch_bounds__(256) kE2(const float* __restrict__ p, float* __restrict__ G){
  int bm = blockIdx.z; int b = bm>>3, m = bm&7;
  int s0 = blockIdx.x*64, t0 = blockIdx.y*64;
  __shared__ float As[64*64];  // [r][d]
  __shared__ float Bs[64*64];  // [d][c]
  int tid = threadIdx.x;
  const float* Ab = p + ((size_t)(b*16+m)*256 + s0)*64;
  const float* Bb = p + ((size_t)(b*16+m+8)*256 + t0)*64;
  for(int idx=tid; idx<1024; idx+=256){
    ((float4*)As)[idx] = ((const float4*)Ab)[idx];
  }
  for(int idx=tid; idx<1024; idx+=256){
    int c = idx & 63, chunk = idx >> 6;   // d0 = chunk*4
    float4 v = ((const float4*)(Bb + c*64))[chunk];
    Bs[(chunk*4+0)*64 + c] = v.x;
    Bs[(chunk*4+1)*64 + c] = v.y;
    Bs[(chunk*4+2)*64 + c] = v.z;
    Bs[(chunk*4+3)*64 + c] = v.w;
  }
  __syncthreads();
  int w = tid>>6, lane = tid&63;
  float acc[16];
  #pragma unroll
  for(int r=0;r<16;r++) acc[r]=0.f;
  #pragma unroll
  for(int ch=0; ch<16; ch++){
    float bv0 = Bs[(ch*4+0)*64+lane];
    float bv1 = Bs[(ch*4+1)*64+lane];
    float bv2 = Bs[(ch*4+2)*64+lane];
    float bv3 = Bs[(ch*4+3)*64+lane];
    #pragma unroll
    for(int r=0;r<16;r++){
      float4 a4 = *(const float4*)&As[(w*16+r)*64 + ch*4];
      acc[r] += a4.x*bv0 + a4.y*bv1 + a4.z*bv2 + a4.w*bv3;
    }
  }
  float* Gp = G + ((size_t)bm*256 + s0 + w*16)*256 + t0 + lane;
  #pragma unroll
  for(int r=0;r<16;r++) Gp[r*256] = acc[r];
}

// D: x = masked mean over i; LN (ln_w/ln_b); x' = xn@W2[j] + b_param
__global__ void kD(const float* __restrict__ xin, const float* __restrict__ er2,
                   const float* __restrict__ mask, const float* __restrict__ W2,
                   const float* __restrict__ lnw, const float* __restrict__ lnb,
                   const float* __restrict__ bp,
                   float* __restrict__ xout, float* __restrict__ xp){
  int st = blockIdx.x, j = blockIdx.y, b = blockIdx.z;
  int tid = threadIdx.x, w = tid>>6, lane = tid&63;
  __shared__ float W2L[4096];
  __shared__ float mcL[16];
  for(int k=tid;k<4096;k+=256) W2L[k]=W2[j*4096+k];
  if(tid<16) mcL[tid]=mask[(b*16+tid)*16+j];
  __syncthreads();
  float lw = lnw[j*64+lane], lb = lnb[j*64+lane];
  #pragma unroll
  for(int ri=0;ri<4;ri++){
    int s = st*16 + w*4 + ri;
    float acc=0.f;
    #pragma unroll
    for(int i=0;i<16;i++){
      acc += er2[((b*16+i)*16+j)*256+s]*mcL[i]*xin[((b*16+i)*256+s)*64+lane];
    }
    float xval = acc*(1.f/16.f);
    int rowo = ((b*16+j)*256+s)*64;
    xout[rowo+lane]=xval;
    float mu = wsum(xval)*(1.f/64.f);
    float dv = xval-mu;
    float var = wsum(dv*dv)*(1.f/64.f);
    float xnv = dv*rsqrtf(var+EPSLN)*lw + lb;
    float acc2 = bp[(j*256+s)*64+lane];
    #pragma unroll 8
    for(int f=0;f<64;f++){
      acc2 += __shfl(xnv,f)*W2L[f*64+lane];
    }
    xp[rowo+lane]=acc2;
  }
}

// F: raw -> softmax -> AV + diag + conv + residuals.
// Wave w owns rows si = w*4..w*4+3 end-to-end: no cross-wave data, 1 barrier.
__global__ void __launch_bounds__(256) kF(
    const float* __restrict__ G, const float* __restrict__ cc,
    const float* __restrict__ muK, const float* __restrict__ rK,
    const float* __restrict__ muQ, const float* __restrict__ rQ,
    const float* __restrict__ xp, const float* __restrict__ cw,
    const float* __restrict__ xarr, const float* __restrict__ temp,
    const float* __restrict__ alpha, const float* __restrict__ beta,
    const float* __restrict__ gamma_, const float* __restrict__ theta,
    float* __restrict__ out){
  int st = blockIdx.x, j = blockIdx.y, b = blockIdx.z;
  int tid = threadIdx.x, w = tid>>6, lane = tid&63;
  __shared__ float probL[16*260];   // [si][t], row stride 260 (16B-aligned)
  float tv = fabsf(temp[0])+1e-4f;
  float inv = 1.f/(sqrtf(512.f)*tv);
  float aM[8];
  #pragma unroll
  for(int m=0;m<8;m++) aM[m]=cc[(b*16+m)*16+j]*cc[(b*16+m+8)*16+j];
  int bj = b*16+j;
  const float* Gb = G + (size_t)(b*8)*65536;
  const float* xpb = xp + (size_t)bj*16384;
  float mQt[4], rQt[4];
  #pragma unroll
  for(int k=0;k<4;k++){
    mQt[k]=muQ[bj*256 + lane + 64*k];
    rQt[k]=rQ [bj*256 + lane + 64*k];
  }
  // softmax rows, wave-local
  #pragma unroll
  for(int q=0;q<4;q++){
    int sidx = w*4+q;
    int s = st*16 + sidx;
    float mKs = 512.f*muK[bj*256+s], rKs = rK[bj*256+s];
    float rv[4];
    #pragma unroll
    for(int k=0;k<4;k++){
      float dot=0.f;
      #pragma unroll
      for(int m=0;m<8;m++) dot += aM[m]*Gb[m*65536 + s*256 + lane + 64*k];
      rv[k] = (dot - mKs*mQt[k])*rKs*rQt[k]*inv;
    }
    float mx = wmax(fmaxf(fmaxf(rv[0],rv[1]),fmaxf(rv[2],rv[3])));
    float e0=expf(rv[0]-mx), e1=expf(rv[1]-mx), e2=expf(rv[2]-mx), e3=expf(rv[3]-mx);
    float isf = 1.f/wsum(e0+e1+e2+e3);
    probL[sidx*260 + lane      ] = e0*isf;
    probL[sidx*260 + lane +  64] = e1*isf;
    probL[sidx*260 + lane + 128] = e2*isf;
    probL[sidx*260 + lane + 192] = e3*isf;
  }
  __syncthreads();   // cheap safety: order ds_writes before cross-lane broadcast reads
  // AV: wave sums ALL t for its own 4 rows
  float accs[4] = {0.f,0.f,0.f,0.f};
  for(int t4=0; t4<64; t4++){
    float xv0 = xpb[(t4*4+0)*64+lane];
    float xv1 = xpb[(t4*4+1)*64+lane];
    float xv2 = xpb[(t4*4+2)*64+lane];
    float xv3 = xpb[(t4*4+3)*64+lane];
    #pragma unroll
    for(int q=0;q<4;q++){
      float4 pr = *(const float4*)&probL[(w*4+q)*260 + t4*4];
      accs[q] += pr.x*xv0 + pr.y*xv1 + pr.z*xv2 + pr.w*xv3;
    }
  }
  float al = fabsf(alpha[j]), be=fabsf(beta[j]), th=fabsf(theta[j]), ga=gamma_[j];
  const float* wq = cw + (j*64+lane)*9;
  float w0=wq[0],w1=wq[1],w2=wq[2],w3v=wq[3],w4=wq[4],w5=wq[5],w6=wq[6],w7=wq[7],w8=wq[8];
  #pragma unroll
  for(int q=0;q<4;q++){
    int sidx = w*4+q;
    int s = st*16+sidx;
    float gl = accs[q];
    int r = s>>4, ci = s&15;
    float cv=0.f;
    #pragma unroll
    for(int dr=0;dr<3;dr++){
      int rr=r+dr-1;
      if(rr<0||rr>15) continue;
      float kw0 = dr==0?w0:(dr==1?w3v:w6);
      float kw1 = dr==0?w1:(dr==1?w4:w7);
      float kw2 = dr==0?w2:(dr==1?w5:w8);
      if(ci>0)  cv += xpb[(rr*16+ci-1)*64+lane]*kw0;
                cv += xpb[(rr*16+ci  )*64+lane]*kw1;
      if(ci<15) cv += xpb[(rr*16+ci+1)*64+lane]*kw2;
    }
    size_t gi = ((size_t)bj*256+s)*64+lane;
    float res = be*gl + al*xpb[s*64+lane] + th*cv + ga*xarr[gi];
    out[gi]=res;
  }
}

extern "C" void kernel_launch(void* const* d_in, const int* in_sizes, int n_in,
                              void* d_out, int out_size, void* d_ws, size_t ws_size,
                              hipStream_t stream) {
  const float* xin = (const float*)d_in[0];
  const float* pxp = (const float*)d_in[1];
  const float* sw  = (const float*)d_in[2];
  const float* bs  = (const float*)d_in[3];
  const float* tau = (const float*)d_in[4];
  const float* temp= (const float*)d_in[5];
  const float* om  = (const float*)d_in[6];
  const float* W2  = (const float*)d_in[7];
  const float* bp  = (const float*)d_in[8];
  const float* lnw = (const float*)d_in[9];
  const float* lnb = (const float*)d_in[10];
  const float* alpha=(const float*)d_in[11];
  const float* beta= (const float*)d_in[12];
  const float* gam = (const float*)d_in[13];
  const float* theta=(const float*)d_in[14];
  const float* cw  = (const float*)d_in[15];
  float* outp = (float*)d_out;
  float* xpo  = outp + 2097152;   // x_prime = second output

  float* ws  = (float*)d_ws;
  float* xe  = ws;                // 32768
  float* xa  = xe + 32768;        // 32768
  float* Sv  = xa + 32768;        // 32768
  float* SSv = Sv + 32768;        // 32768
  float* er2 = SSv + 32768;       // 524288
  float* ee  = er2 + 524288;      // 2048
  float* mask= ee + 2048;         // 2048
  float* ccv = mask + 2048;       // 2048
  float* muK = ccv + 2048;        // 32768
  float* rKv = muK + 32768;       // 32768
  float* muQ = rKv + 32768;       // 32768
  float* rQv = muQ + 32768;       // 32768
  float* Gv  = rQv + 32768;       // 4194304
  float* xv  = Gv + 4194304;      // 2097152

  kA<<<8192,256,0,stream>>>(xin,pxp,xe,xa,Sv,SSv);
  kB<<<128,256,0,stream>>>(xe,sw,bs,om,er2);
  kC1<<<512,256,0,stream>>>(er2,xa,ee);
  kC2<<<8,256,0,stream>>>(ee,tau,temp,mask,ccv);
  kE1<<<128,256,0,stream>>>(Sv,SSv,ccv,muK,rKv,muQ,rQv);
  kE2<<<dim3(4,4,64),256,0,stream>>>(pxp,Gv);
  kD<<<dim3(16,16,8),256,0,stream>>>(xin,er2,mask,W2,lnw,lnb,bp,xv,xpo);
  kF<<<dim3(16,16,8),256,0,stream>>>(Gv,ccv,muK,rKv,muQ,rQv,xpo,cw,xv,temp,
                                     alpha,beta,gam,theta,outp);
}

// Round 3
// 94.234 us; speedup vs baseline: 2.0925x; 1.4505x over previous
//
#include <hip/hip_runtime.h>

#define EPSLN 1e-5f

typedef short bf16x8 __attribute__((ext_vector_type(8)));
typedef float f32x4 __attribute__((ext_vector_type(4)));

__device__ __forceinline__ float wsum(float v){
  #pragma unroll
  for(int o=32;o;o>>=1) v += __shfl_xor(v,o);
  return v;
}
__device__ __forceinline__ float wmax(float v){
  #pragma unroll
  for(int o=32;o;o>>=1) v = fmaxf(v,__shfl_xor(v,o));
  return v;
}
__device__ __forceinline__ unsigned short f2bf(float f){
  unsigned int u = __float_as_uint(f);
  u = (u + 0x7FFFu + ((u>>16)&1u)) >> 16;
  return (unsigned short)u;
}

// A: per (b,i,s) row stats: x_energy, mean|x|, sum p, sum p^2
__global__ void kA(const float* __restrict__ xin, const float* __restrict__ p,
                   float* __restrict__ xe, float* __restrict__ xa,
                   float* __restrict__ Sv, float* __restrict__ SSv){
  int row = blockIdx.x*4 + (threadIdx.x>>6);
  int lane = threadIdx.x & 63;
  float xv = xin[row*64+lane];
  float pv = p[row*64+lane];
  float s1 = wsum(xv);
  float s2 = wsum(fabsf(xv));
  float s3 = wsum(pv);
  float s4 = wsum(pv*pv);
  if(lane==0){ xe[row]=s1*(1.f/64.f); xa[row]=s2*(1.f/64.f); Sv[row]=s3; SSv[row]=s4; }
}

// B: per (b,i): x_norm (max over s), spline basis (4 nonzero coeffs), er2[b,i,j,s]
__global__ void kB(const float* __restrict__ xe, const float* __restrict__ sw,
                   const float* __restrict__ bs, const float* __restrict__ om,
                   float* __restrict__ er2){
  int bi = blockIdx.x;           // (b*16+i)
  int i = bi & 15;
  int tid = threadIdx.x;         // = s
  __shared__ float swL[16*67];
  __shared__ float bsL[16], omL[16];
  __shared__ float red[4];
  for(int k=tid;k<16*67;k+=256) swL[k] = sw[i*16*67 + k];
  if(tid<16){ bsL[tid]=bs[i*16+tid]; omL[tid]=fabsf(om[i*16+tid]); }
  float v = xe[bi*256+tid];
  float m = wmax(fabsf(v));
  if((tid&63)==0) red[tid>>6]=m;
  __syncthreads();
  m = fmaxf(fmaxf(red[0],red[1]),fmaxf(red[2],red[3]));
  float xn = v/(m+1e-8f);
  xn = fminf(fmaxf(xn,-0.99f),0.99f);
  float sil = xn/(1.f+expf(-xn));
  float vv = (xn+1.f)*33.f;          // (x - grid_c)/h = vv - c
  int c0 = (int)floorf(vv)-1;
  float acc[16];
  #pragma unroll
  for(int j=0;j<16;j++) acc[j]=0.f;
  #pragma unroll
  for(int k=0;k<4;k++){
    int c = c0+k;
    if(c<0||c>66) continue;
    float d = fabsf(vv-(float)c);
    float bas = d<1.f ? (2.f/3.f - d*d + d*d*d*0.5f)
              : (d<2.f ? (2.f-d)*(2.f-d)*(2.f-d)*(1.f/6.f) : 0.f);
    #pragma unroll
    for(int j=0;j<16;j++) acc[j] += bas*swL[j*67+c];
  }
  #pragma unroll
  for(int j=0;j<16;j++){
    er2[(bi*16+j)*256+tid] = sil*bsL[j] + acc[j] + omL[j];
  }
}

// C1: edge_energies[b,i,j] = mean_s |er2|*xabs
__global__ void kC1(const float* __restrict__ er2, const float* __restrict__ xa,
                    float* __restrict__ ee){
  int r = blockIdx.x*4 + (threadIdx.x>>6); // (b*16+i)*16+j
  int lane = threadIdx.x&63;
  int bi = r>>4;
  float sum=0.f;
  #pragma unroll
  for(int k=0;k<4;k++){
    int s = lane + k*64;
    sum += fabsf(er2[r*256+s])*xa[bi*256+s];
  }
  sum = wsum(sum);
  if(lane==0) ee[r] = sum*(1.f/256.f);
}

// C2: mask, coefficient c = mult*mask
__global__ void kC2(const float* __restrict__ ee, const float* __restrict__ tau,
                    const float* __restrict__ temp, float* __restrict__ mask,
                    float* __restrict__ cc){
  int g = blockIdx.x*256+threadIdx.x; // 2048 = b*(i*16+j)
  if(g>=2048) return;
  int ij = g & 255;
  float tv = fabsf(temp[0])+1e-4f;
  float ta = fabsf(tau[ij]);
  float e = ee[g];
  float mk = 1.f/(1.f+expf(-(e-ta)/tv));
  mask[g]=mk;
  cc[g]= e/(ta+1e-8f)*mk;
}

// E1: LN stats of K,Q rows from S,SS closed form
__global__ void kE1(const float* __restrict__ Sv, const float* __restrict__ SSv,
                    const float* __restrict__ cc,
                    float* __restrict__ muK, float* __restrict__ rK,
                    float* __restrict__ muQ, float* __restrict__ rQ){
  int bj = blockIdx.x;  // b*16+j
  int b = bj>>4, j = bj&15;
  int s = threadIdx.x;
  float sk=0,ssk=0,sq=0,ssq=0;
  #pragma unroll
  for(int m=0;m<8;m++){
    float ck = cc[(b*16+m)*16+j];
    float cq = cc[(b*16+m+8)*16+j];
    sk  += ck*Sv[(b*16+m)*256+s];
    ssk += ck*ck*SSv[(b*16+m)*256+s];
    sq  += cq*Sv[(b*16+m+8)*256+s];
    ssq += cq*cq*SSv[(b*16+m+8)*256+s];
  }
  float mk = sk*(1.f/512.f);
  float vk = ssk*(1.f/512.f) - mk*mk;
  float mq = sq*(1.f/512.f);
  float vq = ssq*(1.f/512.f) - mq*mq;
  int o = bj*256+s;
  muK[o]=mk; rK[o]=rsqrtf(vk+EPSLN);
  muQ[o]=mq; rQ[o]=rsqrtf(vq+EPSLN);
}

// E2: gram G[b,m,s,t] = sum_d p[b,m,s,d]*p[b,m+8,t,d]
__global__ void __launch_bounds__(256) kE2(const float* __restrict__ p, float* __restrict__ G){
  int bm = blockIdx.z; int b = bm>>3, m = bm&7;
  int s0 = blockIdx.x*64, t0 = blockIdx.y*64;
  __shared__ float As[64*64];  // [r][d]
  __shared__ float Bs[64*64];  // [d][c]
  int tid = threadIdx.x;
  const float* Ab = p + ((size_t)(b*16+m)*256 + s0)*64;
  const float* Bb = p + ((size_t)(b*16+m+8)*256 + t0)*64;
  for(int idx=tid; idx<1024; idx+=256){
    ((float4*)As)[idx] = ((const float4*)Ab)[idx];
  }
  for(int idx=tid; idx<1024; idx+=256){
    int c = idx & 63, chunk = idx >> 6;   // d0 = chunk*4
    float4 v = ((const float4*)(Bb + c*64))[chunk];
    Bs[(chunk*4+0)*64 + c] = v.x;
    Bs[(chunk*4+1)*64 + c] = v.y;
    Bs[(chunk*4+2)*64 + c] = v.z;
    Bs[(chunk*4+3)*64 + c] = v.w;
  }
  __syncthreads();
  int w = tid>>6, lane = tid&63;
  float acc[16];
  #pragma unroll
  for(int r=0;r<16;r++) acc[r]=0.f;
  #pragma unroll
  for(int ch=0; ch<16; ch++){
    float bv0 = Bs[(ch*4+0)*64+lane];
    float bv1 = Bs[(ch*4+1)*64+lane];
    float bv2 = Bs[(ch*4+2)*64+lane];
    float bv3 = Bs[(ch*4+3)*64+lane];
    #pragma unroll
    for(int r=0;r<16;r++){
      float4 a4 = *(const float4*)&As[(w*16+r)*64 + ch*4];
      acc[r] += a4.x*bv0 + a4.y*bv1 + a4.z*bv2 + a4.w*bv3;
    }
  }
  float* Gp = G + ((size_t)bm*256 + s0 + w*16)*256 + t0 + lane;
  #pragma unroll
  for(int r=0;r<16;r++) Gp[r*256] = acc[r];
}

// P: pack W2 (f32 [j][fin][fout]) into bf16 B-fragment order
// elem (k=fin, n=fout) of tile (ks=k>>5, nt=n>>4):
//   lane = ((k>>3)&3)*16 + (n&15), i = k&7
//   flat = ((j*2+ks)*4 + nt)*512 + lane*8 + i
__global__ void kP(const float* __restrict__ W2, unsigned short* __restrict__ w2B){
  int j = blockIdx.x, tid = threadIdx.x;
  for(int idx=tid; idx<4096; idx+=256){
    int f = idx>>6, o = idx&63;
    float v = W2[j*4096 + idx];
    int ks = f>>5, kb = (f>>3)&3, i = f&7;
    int nt = o>>4, col = o&15;
    int lane = kb*16 + col;
    w2B[((j*2+ks)*4 + nt)*512 + lane*8 + i] = f2bf(v);
  }
}

// D: x = masked mean over i; LN; x' = xn@W2[j] via MFMA; emit xpB (bf16 B-frag order)
__global__ void __launch_bounds__(256) kD(
                   const float* __restrict__ xin, const float* __restrict__ er2,
                   const float* __restrict__ mask, const unsigned short* __restrict__ w2B,
                   const float* __restrict__ lnw, const float* __restrict__ lnb,
                   const float* __restrict__ bp,
                   float* __restrict__ xout, float* __restrict__ xp,
                   unsigned short* __restrict__ xpB){
  int st = blockIdx.x, j = blockIdx.y, b = blockIdx.z;
  int tid = threadIdx.x, w = tid>>6, lane = tid&63;
  __shared__ __align__(16) unsigned short xnS[16*64];  // bf16, XOR-swizzled
  __shared__ float mcL[16];
  if(tid<16) mcL[tid]=mask[(b*16+tid)*16+j];
  __syncthreads();
  float lw = lnw[j*64+lane], lb = lnb[j*64+lane];
  int bj = b*16+j;
  unsigned char* xnB = (unsigned char*)xnS;
  #pragma unroll
  for(int ri=0;ri<4;ri++){
    int sl = w*4 + ri;
    int s = st*16 + sl;
    float acc=0.f;
    #pragma unroll
    for(int i=0;i<16;i++){
      acc += er2[((b*16+i)*16+j)*256+s]*mcL[i]*xin[((b*16+i)*256+s)*64+lane];
    }
    float xval = acc*(1.f/16.f);
    xout[((size_t)bj*256+s)*64+lane]=xval;
    float mu = wsum(xval)*(1.f/64.f);
    float dv = xval-mu;
    float var = wsum(dv*dv)*(1.f/64.f);
    float xnv = dv*rsqrtf(var+EPSLN)*lw + lb;
    *(unsigned short*)(xnB + ((sl*128 + lane*2) ^ ((sl&7)<<4))) = f2bf(xnv);
  }
  __syncthreads();
  // MFMA: D[16 s][16 f-tile(nt=w)] = xn[16][64] @ W2[64][64] tile
  f32x4 acc = {0.f,0.f,0.f,0.f};
  int m = lane&15, kb = lane>>4;
  #pragma unroll
  for(int ks=0;ks<2;ks++){
    bf16x8 a = *(const bf16x8*)(xnB + ((m*128 + ks*64 + kb*16) ^ ((m&7)<<4)));
    bf16x8 bfr = *(const bf16x8*)(w2B + ((j*2+ks)*4 + w)*512 + lane*8);
    acc = __builtin_amdgcn_mfma_f32_16x16x32_bf16(a, bfr, acc, 0, 0, 0);
  }
  // epilogue: lane covers si=(kb*4+r), f=w*16+(lane&15)
  int f = w*16 + m;
  unsigned short pk[4];
  #pragma unroll
  for(int r=0;r<4;r++){
    int si = kb*4 + r;
    int s = st*16 + si;
    float xpr = acc[r] + bp[((size_t)j*256+s)*64+f];
    xp[((size_t)bj*256+s)*64+f] = xpr;
    pk[r] = f2bf(xpr);
  }
  int s0 = st*16 + kb*4;
  int flat = ((s0>>5)*4 + w)*512 + ((s0>>3)&3)*128 + m*8 + (s0&7);
  *(ushort4*)(xpB + (size_t)bj*16384 + flat) = *(ushort4*)pk;
}

// F: logits from G -> softmax -> MFMA AV + diag + conv + residuals
__global__ void __launch_bounds__(256) kF(
    const float* __restrict__ G, const float* __restrict__ cc,
    const float* __restrict__ muK, const float* __restrict__ rK,
    const float* __restrict__ muQ, const float* __restrict__ rQ,
    const float* __restrict__ xp, const unsigned short* __restrict__ xpB,
    const float* __restrict__ cw,
    const float* __restrict__ xarr, const float* __restrict__ temp,
    const float* __restrict__ alpha, const float* __restrict__ beta,
    const float* __restrict__ gamma_, const float* __restrict__ theta,
    float* __restrict__ out){
  int st = blockIdx.x, j = blockIdx.y, b = blockIdx.z;
  int tid = threadIdx.x, w = tid>>6, lane = tid&63;
  __shared__ __align__(16) unsigned short probS[16*256];  // bf16, XOR-swizzled
  unsigned char* prB = (unsigned char*)probS;
  float tv = fabsf(temp[0])+1e-4f;
  float inv = 1.f/(sqrtf(512.f)*tv);
  float aM[8];
  #pragma unroll
  for(int m=0;m<8;m++) aM[m]=cc[(b*16+m)*16+j]*cc[(b*16+m+8)*16+j];
  int bj = b*16+j;
  const float* Gb = G + (size_t)(b*8)*65536;
  const float* xpb = xp + (size_t)bj*16384;
  float4 mQ4 = *(const float4*)(muQ + bj*256 + lane*4);
  float4 rQ4 = *(const float4*)(rQ  + bj*256 + lane*4);
  // softmax rows: wave w owns rows si = w*4+q; lane owns t = lane*4..lane*4+3
  #pragma unroll
  for(int q=0;q<4;q++){
    int si = w*4+q;
    int s = st*16 + si;
    float mKs = 512.f*muK[bj*256+s], rKs = rK[bj*256+s];
    float4 dot = {0.f,0.f,0.f,0.f};
    #pragma unroll
    for(int m=0;m<8;m++){
      float4 g4 = *(const float4*)(Gb + m*65536 + s*256 + lane*4);
      dot.x += aM[m]*g4.x; dot.y += aM[m]*g4.y;
      dot.z += aM[m]*g4.z; dot.w += aM[m]*g4.w;
    }
    float r0 = (dot.x - mKs*mQ4.x)*rKs*rQ4.x*inv;
    float r1 = (dot.y - mKs*mQ4.y)*rKs*rQ4.y*inv;
    float r2 = (dot.z - mKs*mQ4.z)*rKs*rQ4.z*inv;
    float r3 = (dot.w - mKs*mQ4.w)*rKs*rQ4.w*inv;
    float mx = wmax(fmaxf(fmaxf(r0,r1),fmaxf(r2,r3)));
    float e0=expf(r0-mx), e1=expf(r1-mx), e2=expf(r2-mx), e3=expf(r3-mx);
    float isf = 1.f/wsum(e0+e1+e2+e3);
    unsigned short pk[4] = {f2bf(e0*isf), f2bf(e1*isf), f2bf(e2*isf), f2bf(e3*isf)};
    *(ushort4*)(prB + ((si*512 + lane*8) ^ ((si&7)<<4))) = *(ushort4*)pk;
  }
  __syncthreads();
  // MFMA AV: D[16 s][16 f(nt=w)] = prob[16][256] @ xp[256][64] tile
  f32x4 acc = {0.f,0.f,0.f,0.f};
  int m = lane&15, kb = lane>>4;
  const unsigned short* xpBb = xpB + (size_t)bj*16384;
  #pragma unroll
  for(int ks=0;ks<8;ks++){
    bf16x8 a = *(const bf16x8*)(prB + ((m*512 + ks*64 + kb*16) ^ ((m&7)<<4)));
    bf16x8 bfr = *(const bf16x8*)(xpBb + ((ks*4 + w)*64 + lane)*8);
    acc = __builtin_amdgcn_mfma_f32_16x16x32_bf16(a, bfr, acc, 0, 0, 0);
  }
  // epilogue: lane -> si=kb*4+r, f=w*16+m; spatial row = st, col = si
  float al = fabsf(alpha[j]), be=fabsf(beta[j]), th=fabsf(theta[j]), ga=gamma_[j];
  int f = w*16 + m;
  const float* wq = cw + (j*64+f)*9;
  float w0=wq[0],w1=wq[1],w2=wq[2],w3v=wq[3],w4=wq[4],w5=wq[5],w6=wq[6],w7=wq[7],w8=wq[8];
  #pragma unroll
  for(int r=0;r<4;r++){
    int si = kb*4 + r;
    int s = st*16 + si;
    float gl = acc[r];
    float cv=0.f;
    #pragma unroll
    for(int dr=0;dr<3;dr++){
      int rr=st+dr-1;
      if(rr<0||rr>15) continue;
      float kw0 = dr==0?w0:(dr==1?w3v:w6);
      float kw1 = dr==0?w1:(dr==1?w4:w7);
      float kw2 = dr==0?w2:(dr==1?w5:w8);
      if(si>0)  cv += xpb[(rr*16+si-1)*64+f]*kw0;
                cv += xpb[(rr*16+si  )*64+f]*kw1;
      if(si<15) cv += xpb[(rr*16+si+1)*64+f]*kw2;
    }
    size_t gi = ((size_t)bj*256+s)*64+f;
    out[gi] = be*gl + al*xpb[s*64+f] + th*cv + ga*xarr[gi];
  }
}

extern "C" void kernel_launch(void* const* d_in, const int* in_sizes, int n_in,
                              void* d_out, int out_size, void* d_ws, size_t ws_size,
                              hipStream_t stream) {
  const float* xin = (const float*)d_in[0];
  const float* pxp = (const float*)d_in[1];
  const float* sw  = (const float*)d_in[2];
  const float* bs  = (const float*)d_in[3];
  const float* tau = (const float*)d_in[4];
  const float* temp= (const float*)d_in[5];
  const float* om  = (const float*)d_in[6];
  const float* W2  = (const float*)d_in[7];
  const float* bp  = (const float*)d_in[8];
  const float* lnw = (const float*)d_in[9];
  const float* lnb = (const float*)d_in[10];
  const float* alpha=(const float*)d_in[11];
  const float* beta= (const float*)d_in[12];
  const float* gam = (const float*)d_in[13];
  const float* theta=(const float*)d_in[14];
  const float* cw  = (const float*)d_in[15];
  float* outp = (float*)d_out;
  float* xpo  = outp + 2097152;   // x_prime = second output

  float* ws  = (float*)d_ws;
  float* xe  = ws;                // 32768
  float* xa  = xe + 32768;        // 32768
  float* Sv  = xa + 32768;        // 32768
  float* SSv = Sv + 32768;        // 32768
  float* er2 = SSv + 32768;       // 524288
  float* ee  = er2 + 524288;      // 2048
  float* mask= ee + 2048;         // 2048
  float* ccv = mask + 2048;       // 2048
  float* muK = ccv + 2048;        // 32768
  float* rKv = muK + 32768;       // 32768
  float* muQ = rKv + 32768;       // 32768
  float* rQv = muQ + 32768;       // 32768
  float* Gv  = rQv + 32768;       // 4194304
  float* xv  = Gv + 4194304;      // 2097152
  unsigned short* xpB = (unsigned short*)(xv + 2097152);   // 2097152 ushorts
  unsigned short* w2B = xpB + 2097152;                     // 65536 ushorts

  kP<<<16,256,0,stream>>>(W2,w2B);
  kA<<<8192,256,0,stream>>>(xin,pxp,xe,xa,Sv,SSv);
  kB<<<128,256,0,stream>>>(xe,sw,bs,om,er2);
  kC1<<<512,256,0,stream>>>(er2,xa,ee);
  kC2<<<8,256,0,stream>>>(ee,tau,temp,mask,ccv);
  kE1<<<128,256,0,stream>>>(Sv,SSv,ccv,muK,rKv,muQ,rQv);
  kE2<<<dim3(4,4,64),256,0,stream>>>(pxp,Gv);
  kD<<<dim3(16,16,8),256,0,stream>>>(xin,er2,mask,w2B,lnw,lnb,bp,xv,xpo,xpB);
  kF<<<dim3(16,16,8),256,0,stream>>>(Gv,ccv,muK,rKv,muQ,rQv,xpo,xpB,cw,xv,temp,
                                     alpha,beta,gam,theta,outp);
}

// Round 4
// 88.214 us; speedup vs baseline: 2.2353x; 1.0682x over previous
//
#include <hip/hip_runtime.h>

#define EPSLN 1e-5f

typedef short bf16x8 __attribute__((ext_vector_type(8)));
typedef float f32x4 __attribute__((ext_vector_type(4)));
typedef unsigned short u16;

__device__ __forceinline__ float wsum(float v){
  #pragma unroll
  for(int o=32;o;o>>=1) v += __shfl_xor(v,o);
  return v;
}
__device__ __forceinline__ float wmax(float v){
  #pragma unroll
  for(int o=32;o;o>>=1) v = fmaxf(v,__shfl_xor(v,o));
  return v;
}
__device__ __forceinline__ u16 f2bf(float f){
  unsigned int u = __float_as_uint(f);
  u = (u + 0x7FFFu + ((u>>16)&1u)) >> 16;
  return (u16)u;
}
__device__ __forceinline__ float bf2f(u16 h){
  return __uint_as_float(((unsigned int)h)<<16);
}

// A: per (b,i,s) row stats + bf16 copies (xin) and hi/lo split (p)
__global__ void kA(const float* __restrict__ xin, const float* __restrict__ p,
                   float* __restrict__ xe, float* __restrict__ xa,
                   float* __restrict__ Sv, float* __restrict__ SSv,
                   u16* __restrict__ xinb, u16* __restrict__ phi, u16* __restrict__ plo){
  int row = blockIdx.x*4 + (threadIdx.x>>6);
  int lane = threadIdx.x & 63;
  float xv = xin[row*64+lane];
  float pv = p[row*64+lane];
  xinb[row*64+lane] = f2bf(xv);
  u16 h = f2bf(pv);
  phi[row*64+lane] = h;
  plo[row*64+lane] = f2bf(pv - bf2f(h));
  float s1 = wsum(xv);
  float s2 = wsum(fabsf(xv));
  float s3 = wsum(pv);
  float s4 = wsum(pv*pv);
  if(lane==0){ xe[row]=s1*(1.f/64.f); xa[row]=s2*(1.f/64.f); Sv[row]=s3; SSv[row]=s4; }
}

// B (fused with C1,C2): spline/er2, edge energies, mask, cc
__global__ void kB(const float* __restrict__ xe, const float* __restrict__ sw,
                   const float* __restrict__ bs, const float* __restrict__ om,
                   const float* __restrict__ xa, const float* __restrict__ tau,
                   const float* __restrict__ temp,
                   float* __restrict__ er2, float* __restrict__ mask,
                   float* __restrict__ cc){
  int bi = blockIdx.x;           // (b*16+i)
  int i = bi & 15;
  int tid = threadIdx.x;         // = s
  int w = tid>>6, lane = tid&63;
  __shared__ float swL[16*67];
  __shared__ float bsL[16], omL[16];
  __shared__ float red[4];
  __shared__ float redE[16][4];
  for(int k=tid;k<16*67;k+=256) swL[k] = sw[i*16*67 + k];
  if(tid<16){ bsL[tid]=bs[i*16+tid]; omL[tid]=fabsf(om[i*16+tid]); }
  float v = xe[bi*256+tid];
  float m = wmax(fabsf(v));
  if(lane==0) red[w]=m;
  __syncthreads();
  m = fmaxf(fmaxf(red[0],red[1]),fmaxf(red[2],red[3]));
  float xn = v/(m+1e-8f);
  xn = fminf(fmaxf(xn,-0.99f),0.99f);
  float sil = xn/(1.f+expf(-xn));
  float vv = (xn+1.f)*33.f;          // (x - grid_c)/h = vv - c
  int c0 = (int)floorf(vv)-1;
  float acc[16];
  #pragma unroll
  for(int j=0;j<16;j++) acc[j]=0.f;
  #pragma unroll
  for(int k=0;k<4;k++){
    int c = c0+k;
    if(c<0||c>66) continue;
    float d = fabsf(vv-(float)c);
    float bas = d<1.f ? (2.f/3.f - d*d + d*d*d*0.5f)
              : (d<2.f ? (2.f-d)*(2.f-d)*(2.f-d)*(1.f/6.f) : 0.f);
    #pragma unroll
    for(int j=0;j<16;j++) acc[j] += bas*swL[j*67+c];
  }
  float xav = xa[bi*256+tid];
  #pragma unroll
  for(int j=0;j<16;j++){
    float ev = sil*bsL[j] + acc[j] + omL[j];
    er2[(bi*16+j)*256+tid] = ev;
    float pe = wsum(fabsf(ev)*xav);
    if(lane==0) redE[j][w]=pe;
  }
  __syncthreads();
  if(tid<16){
    float e = (redE[tid][0]+redE[tid][1]+redE[tid][2]+redE[tid][3])*(1.f/256.f);
    float tv = fabsf(temp[0])+1e-4f;
    float ta = fabsf(tau[i*16+tid]);
    float mk = 1.f/(1.f+expf(-(e-ta)/tv));
    mask[bi*16+tid]=mk;
    cc[bi*16+tid]= e/(ta+1e-8f)*mk;
  }
}

// E1: LN stats of K,Q rows from S,SS closed form
__global__ void kE1(const float* __restrict__ Sv, const float* __restrict__ SSv,
                    const float* __restrict__ cc,
                    float* __restrict__ muK, float* __restrict__ rK,
                    float* __restrict__ muQ, float* __restrict__ rQ){
  int bj = blockIdx.x;  // b*16+j
  int b = bj>>4, j = bj&15;
  int s = threadIdx.x;
  float sk=0,ssk=0,sq=0,ssq=0;
  #pragma unroll
  for(int m=0;m<8;m++){
    float ck = cc[(b*16+m)*16+j];
    float cq = cc[(b*16+m+8)*16+j];
    sk  += ck*Sv[(b*16+m)*256+s];
    ssk += ck*ck*SSv[(b*16+m)*256+s];
    sq  += cq*Sv[(b*16+m+8)*256+s];
    ssq += cq*cq*SSv[(b*16+m+8)*256+s];
  }
  float mk = sk*(1.f/512.f);
  float vk = ssk*(1.f/512.f) - mk*mk;
  float mq = sq*(1.f/512.f);
  float vq = ssq*(1.f/512.f) - mq*mq;
  int o = bj*256+s;
  muK[o]=mk; rK[o]=rsqrtf(vk+EPSLN);
  muQ[o]=mq; rQ[o]=rsqrtf(vq+EPSLN);
}

// E2: gram G[b,m,s,t] = sum_d p[b,m,s,d]*p[b,m+8,t,d] via split-bf16 MFMA
// G = hi*hi + hi*lo + lo*hi (f32 accum), error ~2^-18 rel.
// Block: 64x64 tile; wave w owns s-subtile w (16 s) x all 64 t.
__global__ void __launch_bounds__(256) kE2(const u16* __restrict__ phi,
                                           const u16* __restrict__ plo,
                                           float* __restrict__ G){
  int bm = blockIdx.z; int b = bm>>3, m = bm&7;
  int s0 = blockIdx.x*64, t0 = blockIdx.y*64;
  // frag-ordered: [hi/lo][subtile][ks][lane][8]
  __shared__ __align__(16) u16 Af[2][4][2][64][8];
  __shared__ __align__(16) u16 Bf[2][4][2][64][8];
  int tid = threadIdx.x;
  int row = tid>>2, dseg = tid&3;      // row 0..63, 16 d each
  size_t offA = ((size_t)(b*16+m  )*256 + s0 + row)*64 + dseg*16;
  size_t offB = ((size_t)(b*16+m+8)*256 + t0 + row)*64 + dseg*16;
  int d0 = dseg*16;
  int ks0 = d0>>5, kb0 = (d0>>3)&3;
  int d1 = d0+8;
  int ks1 = d1>>5, kb1 = (d1>>3)&3;
  int lr = row&15, stile = row>>4;
  {
    uint4 v0 = *(const uint4*)(phi + offA);
    uint4 v1 = *(const uint4*)(phi + offA + 8);
    *(uint4*)&Af[0][stile][ks0][kb0*16+lr][0] = v0;
    *(uint4*)&Af[0][stile][ks1][kb1*16+lr][0] = v1;
    uint4 w0 = *(const uint4*)(plo + offA);
    uint4 w1 = *(const uint4*)(plo + offA + 8);
    *(uint4*)&Af[1][stile][ks0][kb0*16+lr][0] = w0;
    *(uint4*)&Af[1][stile][ks1][kb1*16+lr][0] = w1;
    uint4 x0 = *(const uint4*)(phi + offB);
    uint4 x1 = *(const uint4*)(phi + offB + 8);
    *(uint4*)&Bf[0][stile][ks0][kb0*16+lr][0] = x0;
    *(uint4*)&Bf[0][stile][ks1][kb1*16+lr][0] = x1;
    uint4 y0 = *(const uint4*)(plo + offB);
    uint4 y1 = *(const uint4*)(plo + offB + 8);
    *(uint4*)&Bf[1][stile][ks0][kb0*16+lr][0] = y0;
    *(uint4*)&Bf[1][stile][ks1][kb1*16+lr][0] = y1;
  }
  __syncthreads();
  int w = tid>>6, lane = tid&63;
  bf16x8 ah0 = *(const bf16x8*)&Af[0][w][0][lane][0];
  bf16x8 ah1 = *(const bf16x8*)&Af[0][w][1][lane][0];
  bf16x8 al0 = *(const bf16x8*)&Af[1][w][0][lane][0];
  bf16x8 al1 = *(const bf16x8*)&Af[1][w][1][lane][0];
  f32x4 acc[4];
  #pragma unroll
  for(int t=0;t<4;t++) acc[t] = (f32x4){0.f,0.f,0.f,0.f};
  #pragma unroll
  for(int tt=0;tt<4;tt++){
    bf16x8 bh0 = *(const bf16x8*)&Bf[0][tt][0][lane][0];
    bf16x8 bh1 = *(const bf16x8*)&Bf[0][tt][1][lane][0];
    bf16x8 bl0 = *(const bf16x8*)&Bf[1][tt][0][lane][0];
    bf16x8 bl1 = *(const bf16x8*)&Bf[1][tt][1][lane][0];
    acc[tt] = __builtin_amdgcn_mfma_f32_16x16x32_bf16(ah0, bh0, acc[tt], 0,0,0);
    acc[tt] = __builtin_amdgcn_mfma_f32_16x16x32_bf16(ah1, bh1, acc[tt], 0,0,0);
    acc[tt] = __builtin_amdgcn_mfma_f32_16x16x32_bf16(ah0, bl0, acc[tt], 0,0,0);
    acc[tt] = __builtin_amdgcn_mfma_f32_16x16x32_bf16(ah1, bl1, acc[tt], 0,0,0);
    acc[tt] = __builtin_amdgcn_mfma_f32_16x16x32_bf16(al0, bh0, acc[tt], 0,0,0);
    acc[tt] = __builtin_amdgcn_mfma_f32_16x16x32_bf16(al1, bh1, acc[tt], 0,0,0);
  }
  int col = lane&15, r4 = lane>>4;
  #pragma unroll
  for(int tt=0;tt<4;tt++){
    #pragma unroll
    for(int r=0;r<4;r++){
      G[((size_t)bm*256 + s0 + w*16 + r4*4 + r)*256 + t0 + tt*16 + col] = acc[tt][r];
    }
  }
}

// P: pack W2 into bf16 B-fragment order
__global__ void kP(const float* __restrict__ W2, u16* __restrict__ w2B){
  int j = blockIdx.x, tid = threadIdx.x;
  for(int idx=tid; idx<4096; idx+=256){
    int f = idx>>6, o = idx&63;
    float v = W2[j*4096 + idx];
    int ks = f>>5, kb = (f>>3)&3, i = f&7;
    int nt = o>>4, col = o&15;
    int lane = kb*16 + col;
    w2B[((j*2+ks)*4 + nt)*512 + lane*8 + i] = f2bf(v);
  }
}

// D: x = masked mean over i (bf16 xin); LN; x' = xn@W2[j] via MFMA; emit xpB
__global__ void __launch_bounds__(256) kD(
                   const u16* __restrict__ xinb, const float* __restrict__ er2,
                   const float* __restrict__ mask, const u16* __restrict__ w2B,
                   const float* __restrict__ lnw, const float* __restrict__ lnb,
                   const float* __restrict__ bp,
                   float* __restrict__ xout, float* __restrict__ xp,
                   u16* __restrict__ xpB){
  int j = blockIdx.x, st = blockIdx.y, b = blockIdx.z;   // j fastest: xin reuse
  int tid = threadIdx.x, w = tid>>6, lane = tid&63;
  __shared__ __align__(16) u16 xnS[16*64];  // bf16, XOR-swizzled
  __shared__ float mcL[16];
  if(tid<16) mcL[tid]=mask[(b*16+tid)*16+j];
  __syncthreads();
  float lw = lnw[j*64+lane], lb = lnb[j*64+lane];
  int bj = b*16+j;
  unsigned char* xnB = (unsigned char*)xnS;
  #pragma unroll
  for(int ri=0;ri<4;ri++){
    int sl = w*4 + ri;
    int s = st*16 + sl;
    float acc=0.f;
    #pragma unroll
    for(int i=0;i<16;i++){
      acc += er2[((b*16+i)*16+j)*256+s]*mcL[i]*bf2f(xinb[((b*16+i)*256+s)*64+lane]);
    }
    float xval = acc*(1.f/16.f);
    xout[((size_t)bj*256+s)*64+lane]=xval;
    float mu = wsum(xval)*(1.f/64.f);
    float dv = xval-mu;
    float var = wsum(dv*dv)*(1.f/64.f);
    float xnv = dv*rsqrtf(var+EPSLN)*lw + lb;
    *(u16*)(xnB + ((sl*128 + lane*2) ^ ((sl&7)<<4))) = f2bf(xnv);
  }
  __syncthreads();
  // MFMA: D[16 s][16 f-tile(nt=w)] = xn[16][64] @ W2[64][64] tile
  f32x4 acc = {0.f,0.f,0.f,0.f};
  int m = lane&15, kb = lane>>4;
  #pragma unroll
  for(int ks=0;ks<2;ks++){
    bf16x8 a = *(const bf16x8*)(xnB + ((m*128 + ks*64 + kb*16) ^ ((m&7)<<4)));
    bf16x8 bfr = *(const bf16x8*)(w2B + ((j*2+ks)*4 + w)*512 + lane*8);
    acc = __builtin_amdgcn_mfma_f32_16x16x32_bf16(a, bfr, acc, 0, 0, 0);
  }
  int f = w*16 + m;
  u16 pk[4];
  #pragma unroll
  for(int r=0;r<4;r++){
    int si = kb*4 + r;
    int s = st*16 + si;
    float xpr = acc[r] + bp[((size_t)j*256+s)*64+f];
    xp[((size_t)bj*256+s)*64+f] = xpr;
    pk[r] = f2bf(xpr);
  }
  int s0 = st*16 + kb*4;
  int flat = ((s0>>5)*4 + w)*512 + ((s0>>3)&3)*128 + m*8 + (s0&7);
  *(ushort4*)(xpB + (size_t)bj*16384 + flat) = *(ushort4*)pk;
}

// F: logits from G -> softmax -> MFMA AV + diag + conv + residuals
__global__ void __launch_bounds__(256) kF(
    const float* __restrict__ G, const float* __restrict__ cc,
    const float* __restrict__ muK, const float* __restrict__ rK,
    const float* __restrict__ muQ, const float* __restrict__ rQ,
    const float* __restrict__ xp, const u16* __restrict__ xpB,
    const float* __restrict__ cw,
    const float* __restrict__ xarr, const float* __restrict__ temp,
    const float* __restrict__ alpha, const float* __restrict__ beta,
    const float* __restrict__ gamma_, const float* __restrict__ theta,
    float* __restrict__ out){
  int j = blockIdx.x, st = blockIdx.y, b = blockIdx.z;   // j fastest: G reuse
  int tid = threadIdx.x, w = tid>>6, lane = tid&63;
  __shared__ __align__(16) u16 probS[16*256];  // bf16, XOR-swizzled
  unsigned char* prB = (unsigned char*)probS;
  float tv = fabsf(temp[0])+1e-4f;
  float inv = 1.f/(sqrtf(512.f)*tv);
  float aM[8];
  #pragma unroll
  for(int m=0;m<8;m++) aM[m]=cc[(b*16+m)*16+j]*cc[(b*16+m+8)*16+j];
  int bj = b*16+j;
  const float* Gb = G + (size_t)(b*8)*65536;
  const float* xpb = xp + (size_t)bj*16384;
  float4 mQ4 = *(const float4*)(muQ + bj*256 + lane*4);
  float4 rQ4 = *(const float4*)(rQ  + bj*256 + lane*4);
  #pragma unroll
  for(int q=0;q<4;q++){
    int si = w*4+q;
    int s = st*16 + si;
    float mKs = 512.f*muK[bj*256+s], rKs = rK[bj*256+s];
    float4 dot = {0.f,0.f,0.f,0.f};
    #pragma unroll
    for(int m=0;m<8;m++){
      float4 g4 = *(const float4*)(Gb + m*65536 + s*256 + lane*4);
      dot.x += aM[m]*g4.x; dot.y += aM[m]*g4.y;
      dot.z += aM[m]*g4.z; dot.w += aM[m]*g4.w;
    }
    float r0 = (dot.x - mKs*mQ4.x)*rKs*rQ4.x*inv;
    float r1 = (dot.y - mKs*mQ4.y)*rKs*rQ4.y*inv;
    float r2 = (dot.z - mKs*mQ4.z)*rKs*rQ4.z*inv;
    float r3 = (dot.w - mKs*mQ4.w)*rKs*rQ4.w*inv;
    float mx = wmax(fmaxf(fmaxf(r0,r1),fmaxf(r2,r3)));
    float e0=expf(r0-mx), e1=expf(r1-mx), e2=expf(r2-mx), e3=expf(r3-mx);
    float isf = 1.f/wsum(e0+e1+e2+e3);
    u16 pk[4] = {f2bf(e0*isf), f2bf(e1*isf), f2bf(e2*isf), f2bf(e3*isf)};
    *(ushort4*)(prB + ((si*512 + lane*8) ^ ((si&7)<<4))) = *(ushort4*)pk;
  }
  __syncthreads();
  f32x4 acc = {0.f,0.f,0.f,0.f};
  int m = lane&15, kb = lane>>4;
  const u16* xpBb = xpB + (size_t)bj*16384;
  #pragma unroll
  for(int ks=0;ks<8;ks++){
    bf16x8 a = *(const bf16x8*)(prB + ((m*512 + ks*64 + kb*16) ^ ((m&7)<<4)));
    bf16x8 bfr = *(const bf16x8*)(xpBb + ((ks*4 + w)*64 + lane)*8);
    acc = __builtin_amdgcn_mfma_f32_16x16x32_bf16(a, bfr, acc, 0, 0, 0);
  }
  float al = fabsf(alpha[j]), be=fabsf(beta[j]), th=fabsf(theta[j]), ga=gamma_[j];
  int f = w*16 + m;
  const float* wq = cw + (j*64+f)*9;
  float w0=wq[0],w1=wq[1],w2=wq[2],w3v=wq[3],w4=wq[4],w5=wq[5],w6=wq[6],w7=wq[7],w8=wq[8];
  #pragma unroll
  for(int r=0;r<4;r++){
    int si = kb*4 + r;
    int s = st*16 + si;
    float gl = acc[r];
    float cv=0.f;
    #pragma unroll
    for(int dr=0;dr<3;dr++){
      int rr=st+dr-1;
      if(rr<0||rr>15) continue;
      float kw0 = dr==0?w0:(dr==1?w3v:w6);
      float kw1 = dr==0?w1:(dr==1?w4:w7);
      float kw2 = dr==0?w2:(dr==1?w5:w8);
      if(si>0)  cv += xpb[(rr*16+si-1)*64+f]*kw0;
                cv += xpb[(rr*16+si  )*64+f]*kw1;
      if(si<15) cv += xpb[(rr*16+si+1)*64+f]*kw2;
    }
    size_t gi = ((size_t)bj*256+s)*64+f;
    out[gi] = be*gl + al*xpb[s*64+f] + th*cv + ga*xarr[gi];
  }
}

extern "C" void kernel_launch(void* const* d_in, const int* in_sizes, int n_in,
                              void* d_out, int out_size, void* d_ws, size_t ws_size,
                              hipStream_t stream) {
  const float* xin = (const float*)d_in[0];
  const float* pxp = (const float*)d_in[1];
  const float* sw  = (const float*)d_in[2];
  const float* bs  = (const float*)d_in[3];
  const float* tau = (const float*)d_in[4];
  const float* temp= (const float*)d_in[5];
  const float* om  = (const float*)d_in[6];
  const float* W2  = (const float*)d_in[7];
  const float* bp  = (const float*)d_in[8];
  const float* lnw = (const float*)d_in[9];
  const float* lnb = (const float*)d_in[10];
  const float* alpha=(const float*)d_in[11];
  const float* beta= (const float*)d_in[12];
  const float* gam = (const float*)d_in[13];
  const float* theta=(const float*)d_in[14];
  const float* cw  = (const float*)d_in[15];
  float* outp = (float*)d_out;
  float* xpo  = outp + 2097152;   // x_prime = second output

  float* ws  = (float*)d_ws;
  float* xe  = ws;                // 32768
  float* xa  = xe + 32768;        // 32768
  float* Sv  = xa + 32768;        // 32768
  float* SSv = Sv + 32768;        // 32768
  float* er2 = SSv + 32768;       // 524288
  float* mask= er2 + 524288;      // 2048
  float* ccv = mask + 2048;       // 2048
  float* muK = ccv + 2048;        // 32768
  float* rKv = muK + 32768;       // 32768
  float* muQ = rKv + 32768;       // 32768
  float* rQv = muQ + 32768;       // 32768
  float* Gv  = rQv + 32768;       // 4194304
  float* xv  = Gv + 4194304;      // 2097152
  u16* xpB = (u16*)(xv + 2097152);    // 2097152 u16
  u16* w2B = xpB + 2097152;           // 65536 u16
  u16* xinb= w2B + 65536;             // 2097152 u16
  u16* phi = xinb + 2097152;          // 2097152 u16
  u16* plo = phi + 2097152;           // 2097152 u16

  kP<<<16,256,0,stream>>>(W2,w2B);
  kA<<<8192,256,0,stream>>>(xin,pxp,xe,xa,Sv,SSv,xinb,phi,plo);
  kB<<<128,256,0,stream>>>(xe,sw,bs,om,xa,tau,temp,er2,mask,ccv);
  kE1<<<128,256,0,stream>>>(Sv,SSv,ccv,muK,rKv,muQ,rQv);
  kE2<<<dim3(4,4,64),256,0,stream>>>(phi,plo,Gv);
  kD<<<dim3(16,16,8),256,0,stream>>>(xinb,er2,mask,w2B,lnw,lnb,bp,xv,xpo,xpB);
  kF<<<dim3(16,16,8),256,0,stream>>>(Gv,ccv,muK,rKv,muQ,rQv,xpo,xpB,cw,xv,temp,
                                     alpha,beta,gam,theta,outp);
}

// Round 5
// 83.946 us; speedup vs baseline: 2.3489x; 1.0508x over previous
//
#include <hip/hip_runtime.h>

#define EPSLN 1e-5f

typedef short bf16x8 __attribute__((ext_vector_type(8)));
typedef float f32x4 __attribute__((ext_vector_type(4)));
typedef unsigned short u16;

__device__ __forceinline__ float wsum(float v){
  #pragma unroll
  for(int o=32;o;o>>=1) v += __shfl_xor(v,o);
  return v;
}
__device__ __forceinline__ float wmax(float v){
  #pragma unroll
  for(int o=32;o;o>>=1) v = fmaxf(v,__shfl_xor(v,o));
  return v;
}
__device__ __forceinline__ u16 f2bf(float f){
  unsigned int u = __float_as_uint(f);
  u = (u + 0x7FFFu + ((u>>16)&1u)) >> 16;
  return (u16)u;
}
__device__ __forceinline__ float bf2f(u16 h){
  return __uint_as_float(((unsigned int)h)<<16);
}

// A: per (b,i,s) row stats + bf16 copies (xin) and hi/lo split (p).
// Blocks 0..15 additionally pack W2 into bf16 B-fragment order (folded kP).
__global__ void kA(const float* __restrict__ xin, const float* __restrict__ p,
                   const float* __restrict__ W2,
                   float* __restrict__ xe, float* __restrict__ xa,
                   float* __restrict__ Sv, float* __restrict__ SSv,
                   u16* __restrict__ xinb, u16* __restrict__ phi, u16* __restrict__ plo,
                   u16* __restrict__ w2B){
  int row = blockIdx.x*4 + (threadIdx.x>>6);
  int lane = threadIdx.x & 63;
  float xv = xin[row*64+lane];
  float pv = p[row*64+lane];
  xinb[row*64+lane] = f2bf(xv);
  u16 h = f2bf(pv);
  phi[row*64+lane] = h;
  plo[row*64+lane] = f2bf(pv - bf2f(h));
  float s1 = wsum(xv);
  float s2 = wsum(fabsf(xv));
  float s3 = wsum(pv);
  float s4 = wsum(pv*pv);
  if(lane==0){ xe[row]=s1*(1.f/64.f); xa[row]=s2*(1.f/64.f); Sv[row]=s3; SSv[row]=s4; }
  if(blockIdx.x<16){
    int j = blockIdx.x;
    for(int idx=threadIdx.x; idx<4096; idx+=256){
      int f = idx>>6, o = idx&63;
      float v = W2[j*4096 + idx];
      int ks = f>>5, kb = (f>>3)&3, i = f&7;
      int nt = o>>4, col = o&15;
      int ln = kb*16 + col;
      w2B[((j*2+ks)*4 + nt)*512 + ln*8 + i] = f2bf(v);
    }
  }
}

// B (fused C1,C2): spline/er2, edge energies, mask, cc
__global__ void kB(const float* __restrict__ xe, const float* __restrict__ sw,
                   const float* __restrict__ bs, const float* __restrict__ om,
                   const float* __restrict__ xa, const float* __restrict__ tau,
                   const float* __restrict__ temp,
                   float* __restrict__ er2, float* __restrict__ mask,
                   float* __restrict__ cc){
  int bi = blockIdx.x;           // (b*16+i)
  int i = bi & 15;
  int tid = threadIdx.x;         // = s
  int w = tid>>6, lane = tid&63;
  __shared__ float swL[16*67];
  __shared__ float bsL[16], omL[16];
  __shared__ float red[4];
  __shared__ float redE[16][4];
  for(int k=tid;k<16*67;k+=256) swL[k] = sw[i*16*67 + k];
  if(tid<16){ bsL[tid]=bs[i*16+tid]; omL[tid]=fabsf(om[i*16+tid]); }
  float v = xe[bi*256+tid];
  float m = wmax(fabsf(v));
  if(lane==0) red[w]=m;
  __syncthreads();
  m = fmaxf(fmaxf(red[0],red[1]),fmaxf(red[2],red[3]));
  float xn = v/(m+1e-8f);
  xn = fminf(fmaxf(xn,-0.99f),0.99f);
  float sil = xn/(1.f+expf(-xn));
  float vv = (xn+1.f)*33.f;          // (x - grid_c)/h = vv - c
  int c0 = (int)floorf(vv)-1;
  float acc[16];
  #pragma unroll
  for(int j=0;j<16;j++) acc[j]=0.f;
  #pragma unroll
  for(int k=0;k<4;k++){
    int c = c0+k;
    if(c<0||c>66) continue;
    float d = fabsf(vv-(float)c);
    float bas = d<1.f ? (2.f/3.f - d*d + d*d*d*0.5f)
              : (d<2.f ? (2.f-d)*(2.f-d)*(2.f-d)*(1.f/6.f) : 0.f);
    #pragma unroll
    for(int j=0;j<16;j++) acc[j] += bas*swL[j*67+c];
  }
  float xav = xa[bi*256+tid];
  #pragma unroll
  for(int j=0;j<16;j++){
    float ev = sil*bsL[j] + acc[j] + omL[j];
    er2[(bi*16+j)*256+tid] = ev;
    float pe = wsum(fabsf(ev)*xav);
    if(lane==0) redE[j][w]=pe;
  }
  __syncthreads();
  if(tid<16){
    float e = (redE[tid][0]+redE[tid][1]+redE[tid][2]+redE[tid][3])*(1.f/256.f);
    float tv = fabsf(temp[0])+1e-4f;
    float ta = fabsf(tau[i*16+tid]);
    float mk = 1.f/(1.f+expf(-(e-ta)/tv));
    mask[bi*16+tid]=mk;
    cc[bi*16+tid]= e/(ta+1e-8f)*mk;
  }
}

// E2: gram G[b,m,s,t] = sum_d p[b,m,s,d]*p[b,m+8,t,d] via split-bf16 MFMA
__global__ void __launch_bounds__(256) kE2(const u16* __restrict__ phi,
                                           const u16* __restrict__ plo,
                                           float* __restrict__ G){
  int bm = blockIdx.z; int b = bm>>3, m = bm&7;
  int s0 = blockIdx.x*64, t0 = blockIdx.y*64;
  __shared__ __align__(16) u16 Af[2][4][2][64][8];
  __shared__ __align__(16) u16 Bf[2][4][2][64][8];
  int tid = threadIdx.x;
  int row = tid>>2, dseg = tid&3;      // row 0..63, 16 d each
  size_t offA = ((size_t)(b*16+m  )*256 + s0 + row)*64 + dseg*16;
  size_t offB = ((size_t)(b*16+m+8)*256 + t0 + row)*64 + dseg*16;
  int d0 = dseg*16;
  int ks0 = d0>>5, kb0 = (d0>>3)&3;
  int d1 = d0+8;
  int ks1 = d1>>5, kb1 = (d1>>3)&3;
  int lr = row&15, stile = row>>4;
  {
    uint4 v0 = *(const uint4*)(phi + offA);
    uint4 v1 = *(const uint4*)(phi + offA + 8);
    *(uint4*)&Af[0][stile][ks0][kb0*16+lr][0] = v0;
    *(uint4*)&Af[0][stile][ks1][kb1*16+lr][0] = v1;
    uint4 w0 = *(const uint4*)(plo + offA);
    uint4 w1 = *(const uint4*)(plo + offA + 8);
    *(uint4*)&Af[1][stile][ks0][kb0*16+lr][0] = w0;
    *(uint4*)&Af[1][stile][ks1][kb1*16+lr][0] = w1;
    uint4 x0 = *(const uint4*)(phi + offB);
    uint4 x1 = *(const uint4*)(phi + offB + 8);
    *(uint4*)&Bf[0][stile][ks0][kb0*16+lr][0] = x0;
    *(uint4*)&Bf[0][stile][ks1][kb1*16+lr][0] = x1;
    uint4 y0 = *(const uint4*)(plo + offB);
    uint4 y1 = *(const uint4*)(plo + offB + 8);
    *(uint4*)&Bf[1][stile][ks0][kb0*16+lr][0] = y0;
    *(uint4*)&Bf[1][stile][ks1][kb1*16+lr][0] = y1;
  }
  __syncthreads();
  int w = tid>>6, lane = tid&63;
  bf16x8 ah0 = *(const bf16x8*)&Af[0][w][0][lane][0];
  bf16x8 ah1 = *(const bf16x8*)&Af[0][w][1][lane][0];
  bf16x8 al0 = *(const bf16x8*)&Af[1][w][0][lane][0];
  bf16x8 al1 = *(const bf16x8*)&Af[1][w][1][lane][0];
  f32x4 acc[4];
  #pragma unroll
  for(int t=0;t<4;t++) acc[t] = (f32x4){0.f,0.f,0.f,0.f};
  #pragma unroll
  for(int tt=0;tt<4;tt++){
    bf16x8 bh0 = *(const bf16x8*)&Bf[0][tt][0][lane][0];
    bf16x8 bh1 = *(const bf16x8*)&Bf[0][tt][1][lane][0];
    bf16x8 bl0 = *(const bf16x8*)&Bf[1][tt][0][lane][0];
    bf16x8 bl1 = *(const bf16x8*)&Bf[1][tt][1][lane][0];
    acc[tt] = __builtin_amdgcn_mfma_f32_16x16x32_bf16(ah0, bh0, acc[tt], 0,0,0);
    acc[tt] = __builtin_amdgcn_mfma_f32_16x16x32_bf16(ah1, bh1, acc[tt], 0,0,0);
    acc[tt] = __builtin_amdgcn_mfma_f32_16x16x32_bf16(ah0, bl0, acc[tt], 0,0,0);
    acc[tt] = __builtin_amdgcn_mfma_f32_16x16x32_bf16(ah1, bl1, acc[tt], 0,0,0);
    acc[tt] = __builtin_amdgcn_mfma_f32_16x16x32_bf16(al0, bh0, acc[tt], 0,0,0);
    acc[tt] = __builtin_amdgcn_mfma_f32_16x16x32_bf16(al1, bh1, acc[tt], 0,0,0);
  }
  int col = lane&15, r4 = lane>>4;
  #pragma unroll
  for(int tt=0;tt<4;tt++){
    #pragma unroll
    for(int r=0;r<4;r++){
      G[((size_t)bm*256 + s0 + w*16 + r4*4 + r)*256 + t0 + tt*16 + col] = acc[tt][r];
    }
  }
}

// D: x = masked mean over i (bf16 xin); LN; x' = xn@W2[j] via MFMA; emit xpB
__global__ void __launch_bounds__(256) kD(
                   const u16* __restrict__ xinb, const float* __restrict__ er2,
                   const float* __restrict__ mask, const u16* __restrict__ w2B,
                   const float* __restrict__ lnw, const float* __restrict__ lnb,
                   const float* __restrict__ bp,
                   float* __restrict__ xout, float* __restrict__ xp,
                   u16* __restrict__ xpB){
  int j = blockIdx.x, st = blockIdx.y, b = blockIdx.z;   // j fastest: xin reuse
  int tid = threadIdx.x, w = tid>>6, lane = tid&63;
  __shared__ __align__(16) u16 xnS[16*64];  // bf16, XOR-swizzled
  __shared__ float mcL[16];
  if(tid<16) mcL[tid]=mask[(b*16+tid)*16+j];
  __syncthreads();
  float lw = lnw[j*64+lane], lb = lnb[j*64+lane];
  int bj = b*16+j;
  unsigned char* xnB = (unsigned char*)xnS;
  #pragma unroll
  for(int ri=0;ri<4;ri++){
    int sl = w*4 + ri;
    int s = st*16 + sl;
    float acc=0.f;
    #pragma unroll
    for(int i=0;i<16;i++){
      acc += er2[((b*16+i)*16+j)*256+s]*mcL[i]*bf2f(xinb[((b*16+i)*256+s)*64+lane]);
    }
    float xval = acc*(1.f/16.f);
    xout[((size_t)bj*256+s)*64+lane]=xval;
    float mu = wsum(xval)*(1.f/64.f);
    float dv = xval-mu;
    float var = wsum(dv*dv)*(1.f/64.f);
    float xnv = dv*rsqrtf(var+EPSLN)*lw + lb;
    *(u16*)(xnB + ((sl*128 + lane*2) ^ ((sl&7)<<4))) = f2bf(xnv);
  }
  __syncthreads();
  f32x4 acc = {0.f,0.f,0.f,0.f};
  int m = lane&15, kb = lane>>4;
  #pragma unroll
  for(int ks=0;ks<2;ks++){
    bf16x8 a = *(const bf16x8*)(xnB + ((m*128 + ks*64 + kb*16) ^ ((m&7)<<4)));
    bf16x8 bfr = *(const bf16x8*)(w2B + ((j*2+ks)*4 + w)*512 + lane*8);
    acc = __builtin_amdgcn_mfma_f32_16x16x32_bf16(a, bfr, acc, 0, 0, 0);
  }
  int f = w*16 + m;
  u16 pk[4];
  #pragma unroll
  for(int r=0;r<4;r++){
    int si = kb*4 + r;
    int s = st*16 + si;
    float xpr = acc[r] + bp[((size_t)j*256+s)*64+f];
    xp[((size_t)bj*256+s)*64+f] = xpr;
    pk[r] = f2bf(xpr);
  }
  int s0 = st*16 + kb*4;
  int flat = ((s0>>5)*4 + w)*512 + ((s0>>3)&3)*128 + m*8 + (s0&7);
  *(ushort4*)(xpB + (size_t)bj*16384 + flat) = *(ushort4*)pk;
}

// F: 2 j per block; inline LN stats (folded kE1); logits -> softmax -> MFMA AV
//    + diag + conv + residuals.
__global__ void __launch_bounds__(256) kF(
    const float* __restrict__ G, const float* __restrict__ cc,
    const float* __restrict__ Sv, const float* __restrict__ SSv,
    const float* __restrict__ xp, const u16* __restrict__ xpB,
    const float* __restrict__ cw,
    const float* __restrict__ xarr, const float* __restrict__ temp,
    const float* __restrict__ alpha, const float* __restrict__ beta,
    const float* __restrict__ gamma_, const float* __restrict__ theta,
    float* __restrict__ out){
  int jp = blockIdx.x, st = blockIdx.y, b = blockIdx.z;  // jp fastest: G reuse
  int j0 = jp*2, j1 = j0+1;
  int tid = threadIdx.x, w = tid>>6, lane = tid&63;
  __shared__ __align__(16) u16 probS[2][4096];           // bf16, XOR-swizzled
  __shared__ float mKL[2][256], rKL[2][256];
  __shared__ __align__(16) float mQL[2][256], rQL[2][256];
  float tv = fabsf(temp[0])+1e-4f;
  float inv = 1.f/(sqrtf(512.f)*tv);
  float ck0[8],cq0[8],ck1[8],cq1[8],aM0[8],aM1[8];
  #pragma unroll
  for(int m=0;m<8;m++){
    ck0[m]=cc[(b*16+m)*16+j0];  cq0[m]=cc[(b*16+m+8)*16+j0];
    ck1[m]=cc[(b*16+m)*16+j1];  cq1[m]=cc[(b*16+m+8)*16+j1];
    aM0[m]=ck0[m]*cq0[m];       aM1[m]=ck1[m]*cq1[m];
  }
  // LN stats (closed form from row sums), thread t covers row t
  {
    int t = tid;
    float sk0=0,ssk0=0,sq0=0,ssq0=0,sk1=0,ssk1=0,sq1=0,ssq1=0;
    #pragma unroll
    for(int m=0;m<8;m++){
      float svk = Sv [(b*16+m)*256+t];
      float ssvk= SSv[(b*16+m)*256+t];
      float svq = Sv [(b*16+m+8)*256+t];
      float ssvq= SSv[(b*16+m+8)*256+t];
      sk0 += ck0[m]*svk;  ssk0 += ck0[m]*ck0[m]*ssvk;
      sq0 += cq0[m]*svq;  ssq0 += cq0[m]*cq0[m]*ssvq;
      sk1 += ck1[m]*svk;  ssk1 += ck1[m]*ck1[m]*ssvk;
      sq1 += cq1[m]*svq;  ssq1 += cq1[m]*cq1[m]*ssvq;
    }
    float mk0 = sk0*(1.f/512.f), mk1 = sk1*(1.f/512.f);
    float mq0 = sq0*(1.f/512.f), mq1 = sq1*(1.f/512.f);
    mKL[0][t]=mk0; rKL[0][t]=rsqrtf(ssk0*(1.f/512.f)-mk0*mk0+EPSLN);
    mKL[1][t]=mk1; rKL[1][t]=rsqrtf(ssk1*(1.f/512.f)-mk1*mk1+EPSLN);
    mQL[0][t]=mq0; rQL[0][t]=rsqrtf(ssq0*(1.f/512.f)-mq0*mq0+EPSLN);
    mQL[1][t]=mq1; rQL[1][t]=rsqrtf(ssq1*(1.f/512.f)-mq1*mq1+EPSLN);
  }
  __syncthreads();
  int bj0 = b*16+j0, bj1 = b*16+j1;
  const float* Gb = G + (size_t)(b*8)*65536;
  unsigned char* prB0 = (unsigned char*)&probS[0][0];
  unsigned char* prB1 = (unsigned char*)&probS[1][0];
  float4 mQ40 = *(const float4*)&mQL[0][lane*4];
  float4 rQ40 = *(const float4*)&rQL[0][lane*4];
  float4 mQ41 = *(const float4*)&mQL[1][lane*4];
  float4 rQ41 = *(const float4*)&rQL[1][lane*4];
  #pragma unroll
  for(int q=0;q<4;q++){
    int si = w*4+q;
    int s = st*16 + si;
    float4 dot0 = {0.f,0.f,0.f,0.f}, dot1 = {0.f,0.f,0.f,0.f};
    #pragma unroll
    for(int m=0;m<8;m++){
      float4 g4 = *(const float4*)(Gb + (size_t)m*65536 + s*256 + lane*4);
      dot0.x += aM0[m]*g4.x; dot0.y += aM0[m]*g4.y;
      dot0.z += aM0[m]*g4.z; dot0.w += aM0[m]*g4.w;
      dot1.x += aM1[m]*g4.x; dot1.y += aM1[m]*g4.y;
      dot1.z += aM1[m]*g4.z; dot1.w += aM1[m]*g4.w;
    }
    {
      float mKs = 512.f*mKL[0][s], rKs = rKL[0][s];
      float r0 = (dot0.x - mKs*mQ40.x)*rKs*rQ40.x*inv;
      float r1 = (dot0.y - mKs*mQ40.y)*rKs*rQ40.y*inv;
      float r2 = (dot0.z - mKs*mQ40.z)*rKs*rQ40.z*inv;
      float r3 = (dot0.w - mKs*mQ40.w)*rKs*rQ40.w*inv;
      float mx = wmax(fmaxf(fmaxf(r0,r1),fmaxf(r2,r3)));
      float e0=expf(r0-mx), e1=expf(r1-mx), e2=expf(r2-mx), e3=expf(r3-mx);
      float isf = 1.f/wsum(e0+e1+e2+e3);
      u16 pk[4] = {f2bf(e0*isf), f2bf(e1*isf), f2bf(e2*isf), f2bf(e3*isf)};
      *(ushort4*)(prB0 + ((si*512 + lane*8) ^ ((si&7)<<4))) = *(ushort4*)pk;
    }
    {
      float mKs = 512.f*mKL[1][s], rKs = rKL[1][s];
      float r0 = (dot1.x - mKs*mQ41.x)*rKs*rQ41.x*inv;
      float r1 = (dot1.y - mKs*mQ41.y)*rKs*rQ41.y*inv;
      float r2 = (dot1.z - mKs*mQ41.z)*rKs*rQ41.z*inv;
      float r3 = (dot1.w - mKs*mQ41.w)*rKs*rQ41.w*inv;
      float mx = wmax(fmaxf(fmaxf(r0,r1),fmaxf(r2,r3)));
      float e0=expf(r0-mx), e1=expf(r1-mx), e2=expf(r2-mx), e3=expf(r3-mx);
      float isf = 1.f/wsum(e0+e1+e2+e3);
      u16 pk[4] = {f2bf(e0*isf), f2bf(e1*isf), f2bf(e2*isf), f2bf(e3*isf)};
      *(ushort4*)(prB1 + ((si*512 + lane*8) ^ ((si&7)<<4))) = *(ushort4*)pk;
    }
  }
  __syncthreads();
  int m_ = lane&15, kb = lane>>4;
  f32x4 acc0 = {0.f,0.f,0.f,0.f}, acc1 = {0.f,0.f,0.f,0.f};
  const u16* xpB0 = xpB + (size_t)bj0*16384;
  const u16* xpB1 = xpB + (size_t)bj1*16384;
  #pragma unroll
  for(int ks=0;ks<8;ks++){
    int aoff = (m_*512 + ks*64 + kb*16) ^ ((m_&7)<<4);
    int boff = ((ks*4 + w)*64 + lane)*8;
    bf16x8 a0 = *(const bf16x8*)(prB0 + aoff);
    bf16x8 a1 = *(const bf16x8*)(prB1 + aoff);
    acc0 = __builtin_amdgcn_mfma_f32_16x16x32_bf16(a0, *(const bf16x8*)(xpB0 + boff), acc0, 0,0,0);
    acc1 = __builtin_amdgcn_mfma_f32_16x16x32_bf16(a1, *(const bf16x8*)(xpB1 + boff), acc1, 0,0,0);
  }
  int f = w*16 + m_;
  #pragma unroll
  for(int jj=0;jj<2;jj++){
    int j = j0+jj;
    int bj = b*16+j;
    const float* xpb = xp + (size_t)bj*16384;
    f32x4 acc = jj ? acc1 : acc0;
    float al = fabsf(alpha[j]), be=fabsf(beta[j]), th=fabsf(theta[j]), ga=gamma_[j];
    const float* wq = cw + (j*64+f)*9;
    float w0=wq[0],w1=wq[1],w2=wq[2],w3v=wq[3],w4=wq[4],w5=wq[5],w6=wq[6],w7=wq[7],w8=wq[8];
    #pragma unroll
    for(int r=0;r<4;r++){
      int si = kb*4 + r;
      int s = st*16 + si;
      float gl = acc[r];
      float cv=0.f;
      #pragma unroll
      for(int dr=0;dr<3;dr++){
        int rr=st+dr-1;
        if(rr<0||rr>15) continue;
        float kw0 = dr==0?w0:(dr==1?w3v:w6);
        float kw1 = dr==0?w1:(dr==1?w4:w7);
        float kw2 = dr==0?w2:(dr==1?w5:w8);
        if(si>0)  cv += xpb[(rr*16+si-1)*64+f]*kw0;
                  cv += xpb[(rr*16+si  )*64+f]*kw1;
        if(si<15) cv += xpb[(rr*16+si+1)*64+f]*kw2;
      }
      size_t gi = ((size_t)bj*256+s)*64+f;
      out[gi] = be*gl + al*xpb[s*64+f] + th*cv + ga*xarr[gi];
    }
  }
}

extern "C" void kernel_launch(void* const* d_in, const int* in_sizes, int n_in,
                              void* d_out, int out_size, void* d_ws, size_t ws_size,
                              hipStream_t stream) {
  const float* xin = (const float*)d_in[0];
  const float* pxp = (const float*)d_in[1];
  const float* sw  = (const float*)d_in[2];
  const float* bs  = (const float*)d_in[3];
  const float* tau = (const float*)d_in[4];
  const float* temp= (const float*)d_in[5];
  const float* om  = (const float*)d_in[6];
  const float* W2  = (const float*)d_in[7];
  const float* bp  = (const float*)d_in[8];
  const float* lnw = (const float*)d_in[9];
  const float* lnb = (const float*)d_in[10];
  const float* alpha=(const float*)d_in[11];
  const float* beta= (const float*)d_in[12];
  const float* gam = (const float*)d_in[13];
  const float* theta=(const float*)d_in[14];
  const float* cw  = (const float*)d_in[15];
  float* outp = (float*)d_out;
  float* xpo  = outp + 2097152;   // x_prime = second output

  float* ws  = (float*)d_ws;
  float* xe  = ws;                // 32768
  float* xa  = xe + 32768;        // 32768
  float* Sv  = xa + 32768;        // 32768
  float* SSv = Sv + 32768;        // 32768
  float* er2 = SSv + 32768;       // 524288
  float* mask= er2 + 524288;      // 2048
  float* ccv = mask + 2048;       // 2048
  float* Gv  = ccv + 2048;        // 4194304
  float* xv  = Gv + 4194304;      // 2097152
  u16* xpB = (u16*)(xv + 2097152);    // 2097152 u16
  u16* w2B = xpB + 2097152;           // 65536 u16
  u16* xinb= w2B + 65536;             // 2097152 u16
  u16* phi = xinb + 2097152;          // 2097152 u16
  u16* plo = phi + 2097152;           // 2097152 u16

  kA<<<8192,256,0,stream>>>(xin,pxp,W2,xe,xa,Sv,SSv,xinb,phi,plo,w2B);
  kB<<<128,256,0,stream>>>(xe,sw,bs,om,xa,tau,temp,er2,mask,ccv);
  kE2<<<dim3(4,4,64),256,0,stream>>>(phi,plo,Gv);
  kD<<<dim3(16,16,8),256,0,stream>>>(xinb,er2,mask,w2B,lnw,lnb,bp,xv,xpo,xpB);
  kF<<<dim3(8,16,8),256,0,stream>>>(Gv,ccv,Sv,SSv,xpo,xpB,cw,xv,temp,
                                    alpha,beta,gam,theta,outp);
}

// Round 6
// 75.319 us; speedup vs baseline: 2.6180x; 1.1145x over previous
//
#include <hip/hip_runtime.h>

#define EPSLN 1e-5f

typedef short bf16x8 __attribute__((ext_vector_type(8)));
typedef float f32x4 __attribute__((ext_vector_type(4)));
typedef unsigned short u16;
typedef unsigned short u16x8 __attribute__((ext_vector_type(8)));

__device__ __forceinline__ float wsum(float v){
  #pragma unroll
  for(int o=32;o;o>>=1) v += __shfl_xor(v,o);
  return v;
}
__device__ __forceinline__ float wmax(float v){
  #pragma unroll
  for(int o=32;o;o>>=1) v = fmaxf(v,__shfl_xor(v,o));
  return v;
}
__device__ __forceinline__ u16 f2bf(float f){
  unsigned int u = __float_as_uint(f);
  u = (u + 0x7FFFu + ((u>>16)&1u)) >> 16;
  return (u16)u;
}
__device__ __forceinline__ float bf2f(u16 h){
  return __uint_as_float(((unsigned int)h)<<16);
}

// A v2: quarter-row per thread. Stats via 2-shuffle 4-lane reduce.
// Blocks 0..15 also pack W2 into bf16 B-fragment order.
__global__ void __launch_bounds__(256) kA(
                   const float* __restrict__ xin, const float* __restrict__ p,
                   const float* __restrict__ W2,
                   float* __restrict__ xe, float* __restrict__ xa,
                   float* __restrict__ Sv, float* __restrict__ SSv,
                   u16* __restrict__ xinb, u16* __restrict__ phi, u16* __restrict__ plo,
                   u16* __restrict__ w2B){
  int t = threadIdx.x;
  int rl = t>>2, q = t&3;
  int row = blockIdx.x*64 + rl;
  const float4* xr = (const float4*)(xin + row*64 + q*16);
  const float4* pr = (const float4*)(p   + row*64 + q*16);
  float s1=0.f,s2=0.f,s3=0.f,s4=0.f;
  u16x8 xb[2], ph[2], pl[2];
  #pragma unroll
  for(int k=0;k<4;k++){
    float4 xv = xr[k];
    float4 pv = pr[k];
    s1 += xv.x+xv.y+xv.z+xv.w;
    s2 += fabsf(xv.x)+fabsf(xv.y)+fabsf(xv.z)+fabsf(xv.w);
    s3 += pv.x+pv.y+pv.z+pv.w;
    s4 += pv.x*pv.x+pv.y*pv.y+pv.z*pv.z+pv.w*pv.w;
    int h = k>>1, o = (k&1)*4;
    xb[h][o+0]=f2bf(xv.x); xb[h][o+1]=f2bf(xv.y);
    xb[h][o+2]=f2bf(xv.z); xb[h][o+3]=f2bf(xv.w);
    u16 h0=f2bf(pv.x), h1=f2bf(pv.y), h2=f2bf(pv.z), h3=f2bf(pv.w);
    ph[h][o+0]=h0; ph[h][o+1]=h1; ph[h][o+2]=h2; ph[h][o+3]=h3;
    pl[h][o+0]=f2bf(pv.x-bf2f(h0)); pl[h][o+1]=f2bf(pv.y-bf2f(h1));
    pl[h][o+2]=f2bf(pv.z-bf2f(h2)); pl[h][o+3]=f2bf(pv.w-bf2f(h3));
  }
  *(u16x8*)(xinb + row*64 + q*16    ) = xb[0];
  *(u16x8*)(xinb + row*64 + q*16 + 8) = xb[1];
  *(u16x8*)(phi  + row*64 + q*16    ) = ph[0];
  *(u16x8*)(phi  + row*64 + q*16 + 8) = ph[1];
  *(u16x8*)(plo  + row*64 + q*16    ) = pl[0];
  *(u16x8*)(plo  + row*64 + q*16 + 8) = pl[1];
  s1 += __shfl_xor(s1,1); s1 += __shfl_xor(s1,2);
  s2 += __shfl_xor(s2,1); s2 += __shfl_xor(s2,2);
  s3 += __shfl_xor(s3,1); s3 += __shfl_xor(s3,2);
  s4 += __shfl_xor(s4,1); s4 += __shfl_xor(s4,2);
  if(q==0){ xe[row]=s1*(1.f/64.f); xa[row]=s2*(1.f/64.f); Sv[row]=s3; SSv[row]=s4; }
  if(blockIdx.x<16){
    int j = blockIdx.x;
    for(int idx=threadIdx.x; idx<4096; idx+=256){
      int f = idx>>6, o = idx&63;
      float v = W2[j*4096 + idx];
      int ks = f>>5, kb = (f>>3)&3, i = f&7;
      int nt = o>>4, col = o&15;
      int ln = kb*16 + col;
      w2B[((j*2+ks)*4 + nt)*512 + ln*8 + i] = f2bf(v);
    }
  }
}

// BE: fused kB (blocks 0..127) + kE2 gram MFMA (blocks 128..1151). 32KB LDS union.
__global__ void __launch_bounds__(256) kBE(
                   const float* __restrict__ xe, const float* __restrict__ sw,
                   const float* __restrict__ bs, const float* __restrict__ om,
                   const float* __restrict__ xa, const float* __restrict__ tau,
                   const float* __restrict__ temp,
                   float* __restrict__ er2, float* __restrict__ mask,
                   float* __restrict__ cc,
                   const u16* __restrict__ phi, const u16* __restrict__ plo,
                   float* __restrict__ G){
  __shared__ __align__(16) unsigned char shm[32768];
  int tid = threadIdx.x;
  if(blockIdx.x < 128){
    // ---- kB body ----
    float* swL = (float*)shm;          // 1072
    float* bsL = swL + 1072;           // 16
    float* omL = bsL + 16;             // 16
    float* red = omL + 16;             // 4
    float* redE= red + 4;              // [16][4]
    int bi = blockIdx.x;
    int i = bi & 15;
    int w = tid>>6, lane = tid&63;
    for(int k=tid;k<16*67;k+=256) swL[k] = sw[i*16*67 + k];
    if(tid<16){ bsL[tid]=bs[i*16+tid]; omL[tid]=fabsf(om[i*16+tid]); }
    float v = xe[bi*256+tid];
    float m = wmax(fabsf(v));
    if(lane==0) red[w]=m;
    __syncthreads();
    m = fmaxf(fmaxf(red[0],red[1]),fmaxf(red[2],red[3]));
    float xn = v/(m+1e-8f);
    xn = fminf(fmaxf(xn,-0.99f),0.99f);
    float sil = xn/(1.f+expf(-xn));
    float vv = (xn+1.f)*33.f;
    int c0 = (int)floorf(vv)-1;
    float acc[16];
    #pragma unroll
    for(int j=0;j<16;j++) acc[j]=0.f;
    #pragma unroll
    for(int k=0;k<4;k++){
      int c = c0+k;
      if(c<0||c>66) continue;
      float d = fabsf(vv-(float)c);
      float bas = d<1.f ? (2.f/3.f - d*d + d*d*d*0.5f)
                : (d<2.f ? (2.f-d)*(2.f-d)*(2.f-d)*(1.f/6.f) : 0.f);
      #pragma unroll
      for(int j=0;j<16;j++) acc[j] += bas*swL[j*67+c];
    }
    float xav = xa[bi*256+tid];
    #pragma unroll
    for(int j=0;j<16;j++){
      float ev = sil*bsL[j] + acc[j] + omL[j];
      er2[(bi*16+j)*256+tid] = ev;
      float pe = wsum(fabsf(ev)*xav);
      if(lane==0) redE[j*4+w]=pe;
    }
    __syncthreads();
    if(tid<16){
      float e = (redE[tid*4+0]+redE[tid*4+1]+redE[tid*4+2]+redE[tid*4+3])*(1.f/256.f);
      float tv = fabsf(temp[0])+1e-4f;
      float ta = fabsf(tau[i*16+tid]);
      float mk = 1.f/(1.f+expf(-(e-ta)/tv));
      mask[bi*16+tid]=mk;
      cc[bi*16+tid]= e/(ta+1e-8f)*mk;
    }
  } else {
    // ---- kE2 body ----
    u16* AfB = (u16*)shm;           // [2][4][2][64][8] = 8192 u16
    u16* BfB = AfB + 8192;
    int e = blockIdx.x - 128;
    int sx = e&3, ty = (e>>2)&3, bm = e>>4;
    int b = bm>>3, m = bm&7;
    int s0 = sx*64, t0 = ty*64;
    int row = tid>>2, dseg = tid&3;
    size_t offA = ((size_t)(b*16+m  )*256 + s0 + row)*64 + dseg*16;
    size_t offB = ((size_t)(b*16+m+8)*256 + t0 + row)*64 + dseg*16;
    int d0 = dseg*16;
    int ks0 = d0>>5, kb0 = (d0>>3)&3;
    int ks1 = (d0+8)>>5, kb1 = ((d0+8)>>3)&3;
    int lr = row&15, stile = row>>4;
    #define AOFF(h,stl,ks,ln) (((((h)*4+(stl))*2+(ks))*64 + (ln))*8)
    {
      uint4 v0 = *(const uint4*)(phi + offA);
      uint4 v1 = *(const uint4*)(phi + offA + 8);
      *(uint4*)(AfB + AOFF(0,stile,ks0,kb0*16+lr)) = v0;
      *(uint4*)(AfB + AOFF(0,stile,ks1,kb1*16+lr)) = v1;
      uint4 w0 = *(const uint4*)(plo + offA);
      uint4 w1 = *(const uint4*)(plo + offA + 8);
      *(uint4*)(AfB + AOFF(1,stile,ks0,kb0*16+lr)) = w0;
      *(uint4*)(AfB + AOFF(1,stile,ks1,kb1*16+lr)) = w1;
      uint4 x0 = *(const uint4*)(phi + offB);
      uint4 x1 = *(const uint4*)(phi + offB + 8);
      *(uint4*)(BfB + AOFF(0,stile,ks0,kb0*16+lr)) = x0;
      *(uint4*)(BfB + AOFF(0,stile,ks1,kb1*16+lr)) = x1;
      uint4 y0 = *(const uint4*)(plo + offB);
      uint4 y1 = *(const uint4*)(plo + offB + 8);
      *(uint4*)(BfB + AOFF(1,stile,ks0,kb0*16+lr)) = y0;
      *(uint4*)(BfB + AOFF(1,stile,ks1,kb1*16+lr)) = y1;
    }
    __syncthreads();
    int w = tid>>6, lane = tid&63;
    bf16x8 ah0 = *(const bf16x8*)(AfB + AOFF(0,w,0,lane));
    bf16x8 ah1 = *(const bf16x8*)(AfB + AOFF(0,w,1,lane));
    bf16x8 al0 = *(const bf16x8*)(AfB + AOFF(1,w,0,lane));
    bf16x8 al1 = *(const bf16x8*)(AfB + AOFF(1,w,1,lane));
    f32x4 acc[4];
    #pragma unroll
    for(int tt=0;tt<4;tt++) acc[tt] = (f32x4){0.f,0.f,0.f,0.f};
    #pragma unroll
    for(int tt=0;tt<4;tt++){
      bf16x8 bh0 = *(const bf16x8*)(BfB + AOFF(0,tt,0,lane));
      bf16x8 bh1 = *(const bf16x8*)(BfB + AOFF(0,tt,1,lane));
      bf16x8 bl0 = *(const bf16x8*)(BfB + AOFF(1,tt,0,lane));
      bf16x8 bl1 = *(const bf16x8*)(BfB + AOFF(1,tt,1,lane));
      acc[tt] = __builtin_amdgcn_mfma_f32_16x16x32_bf16(ah0, bh0, acc[tt], 0,0,0);
      acc[tt] = __builtin_amdgcn_mfma_f32_16x16x32_bf16(ah1, bh1, acc[tt], 0,0,0);
      acc[tt] = __builtin_amdgcn_mfma_f32_16x16x32_bf16(ah0, bl0, acc[tt], 0,0,0);
      acc[tt] = __builtin_amdgcn_mfma_f32_16x16x32_bf16(ah1, bl1, acc[tt], 0,0,0);
      acc[tt] = __builtin_amdgcn_mfma_f32_16x16x32_bf16(al0, bh0, acc[tt], 0,0,0);
      acc[tt] = __builtin_amdgcn_mfma_f32_16x16x32_bf16(al1, bh1, acc[tt], 0,0,0);
    }
    int col = lane&15, r4 = lane>>4;
    #pragma unroll
    for(int tt=0;tt<4;tt++){
      #pragma unroll
      for(int r=0;r<4;r++){
        G[((size_t)bm*256 + s0 + w*16 + r4*4 + r)*256 + t0 + tt*16 + col] = acc[tt][r];
      }
    }
    #undef AOFF
  }
}

// D: x = masked mean over i (bf16 xin); LN; x' = xn@W2[j] via MFMA; emit xpB
__global__ void __launch_bounds__(256) kD(
                   const u16* __restrict__ xinb, const float* __restrict__ er2,
                   const float* __restrict__ mask, const u16* __restrict__ w2B,
                   const float* __restrict__ lnw, const float* __restrict__ lnb,
                   const float* __restrict__ bp,
                   float* __restrict__ xout, float* __restrict__ xp,
                   u16* __restrict__ xpB){
  int j = blockIdx.x, st = blockIdx.y, b = blockIdx.z;   // j fastest: xin reuse
  int tid = threadIdx.x, w = tid>>6, lane = tid&63;
  __shared__ __align__(16) u16 xnS[16*64];  // bf16, XOR-swizzled
  __shared__ float mcL[16];
  if(tid<16) mcL[tid]=mask[(b*16+tid)*16+j];
  __syncthreads();
  float lw = lnw[j*64+lane], lb = lnb[j*64+lane];
  int bj = b*16+j;
  unsigned char* xnB = (unsigned char*)xnS;
  #pragma unroll
  for(int ri=0;ri<4;ri++){
    int sl = w*4 + ri;
    int s = st*16 + sl;
    float acc=0.f;
    #pragma unroll
    for(int i=0;i<16;i++){
      acc += er2[((b*16+i)*16+j)*256+s]*mcL[i]*bf2f(xinb[((b*16+i)*256+s)*64+lane]);
    }
    float xval = acc*(1.f/16.f);
    xout[((size_t)bj*256+s)*64+lane]=xval;
    float mu = wsum(xval)*(1.f/64.f);
    float dv = xval-mu;
    float var = wsum(dv*dv)*(1.f/64.f);
    float xnv = dv*rsqrtf(var+EPSLN)*lw + lb;
    *(u16*)(xnB + ((sl*128 + lane*2) ^ ((sl&7)<<4))) = f2bf(xnv);
  }
  __syncthreads();
  f32x4 acc = {0.f,0.f,0.f,0.f};
  int m = lane&15, kb = lane>>4;
  #pragma unroll
  for(int ks=0;ks<2;ks++){
    bf16x8 a = *(const bf16x8*)(xnB + ((m*128 + ks*64 + kb*16) ^ ((m&7)<<4)));
    bf16x8 bfr = *(const bf16x8*)(w2B + ((j*2+ks)*4 + w)*512 + lane*8);
    acc = __builtin_amdgcn_mfma_f32_16x16x32_bf16(a, bfr, acc, 0, 0, 0);
  }
  int f = w*16 + m;
  u16 pk[4];
  #pragma unroll
  for(int r=0;r<4;r++){
    int si = kb*4 + r;
    int s = st*16 + si;
    float xpr = acc[r] + bp[((size_t)j*256+s)*64+f];
    xp[((size_t)bj*256+s)*64+f] = xpr;
    pk[r] = f2bf(xpr);
  }
  int s0 = st*16 + kb*4;
  int flat = ((s0>>5)*4 + w)*512 + ((s0>>3)&3)*128 + m*8 + (s0&7);
  *(ushort4*)(xpB + (size_t)bj*16384 + flat) = *(ushort4*)pk;
}

// F: 2 j per block; inline LN stats; logits -> softmax -> MFMA AV;
//    conv via LDS-staged xp window (overlaid on probS); residuals.
__global__ void __launch_bounds__(256) kF(
    const float* __restrict__ G, const float* __restrict__ cc,
    const float* __restrict__ Sv, const float* __restrict__ SSv,
    const float* __restrict__ xp, const u16* __restrict__ xpB,
    const float* __restrict__ cw,
    const float* __restrict__ xarr, const float* __restrict__ temp,
    const float* __restrict__ alpha, const float* __restrict__ beta,
    const float* __restrict__ gamma_, const float* __restrict__ theta,
    float* __restrict__ out){
  int jp = blockIdx.x, st = blockIdx.y, b = blockIdx.z;  // jp fastest: G reuse
  int j0 = jp*2, j1 = j0+1;
  int tid = threadIdx.x, w = tid>>6, lane = tid&63;
  __shared__ __align__(16) unsigned char ovl[26112];     // probS (16KB) / xpT (25.5KB)
  __shared__ float mKL[2][256], rKL[2][256];
  __shared__ __align__(16) float mQL[2][256], rQL[2][256];
  unsigned char* prB0 = ovl;
  unsigned char* prB1 = ovl + 8192;
  float* xpT = (float*)ovl;                              // [2][3][16][68]
  float tv = fabsf(temp[0])+1e-4f;
  float inv = 1.f/(sqrtf(512.f)*tv);
  float ck0[8],cq0[8],ck1[8],cq1[8],aM0[8],aM1[8];
  #pragma unroll
  for(int m=0;m<8;m++){
    ck0[m]=cc[(b*16+m)*16+j0];  cq0[m]=cc[(b*16+m+8)*16+j0];
    ck1[m]=cc[(b*16+m)*16+j1];  cq1[m]=cc[(b*16+m+8)*16+j1];
    aM0[m]=ck0[m]*cq0[m];       aM1[m]=ck1[m]*cq1[m];
  }
  {
    int t = tid;
    float sk0=0,ssk0=0,sq0=0,ssq0=0,sk1=0,ssk1=0,sq1=0,ssq1=0;
    #pragma unroll
    for(int m=0;m<8;m++){
      float svk = Sv [(b*16+m)*256+t];
      float ssvk= SSv[(b*16+m)*256+t];
      float svq = Sv [(b*16+m+8)*256+t];
      float ssvq= SSv[(b*16+m+8)*256+t];
      sk0 += ck0[m]*svk;  ssk0 += ck0[m]*ck0[m]*ssvk;
      sq0 += cq0[m]*svq;  ssq0 += cq0[m]*cq0[m]*ssvq;
      sk1 += ck1[m]*svk;  ssk1 += ck1[m]*ck1[m]*ssvk;
      sq1 += cq1[m]*svq;  ssq1 += cq1[m]*cq1[m]*ssvq;
    }
    float mk0 = sk0*(1.f/512.f), mk1 = sk1*(1.f/512.f);
    float mq0 = sq0*(1.f/512.f), mq1 = sq1*(1.f/512.f);
    mKL[0][t]=mk0; rKL[0][t]=rsqrtf(ssk0*(1.f/512.f)-mk0*mk0+EPSLN);
    mKL[1][t]=mk1; rKL[1][t]=rsqrtf(ssk1*(1.f/512.f)-mk1*mk1+EPSLN);
    mQL[0][t]=mq0; rQL[0][t]=rsqrtf(ssq0*(1.f/512.f)-mq0*mq0+EPSLN);
    mQL[1][t]=mq1; rQL[1][t]=rsqrtf(ssq1*(1.f/512.f)-mq1*mq1+EPSLN);
  }
  __syncthreads();
  int bj0 = b*16+j0, bj1 = b*16+j1;
  const float* Gb = G + (size_t)(b*8)*65536;
  float4 mQ40 = *(const float4*)&mQL[0][lane*4];
  float4 rQ40 = *(const float4*)&rQL[0][lane*4];
  float4 mQ41 = *(const float4*)&mQL[1][lane*4];
  float4 rQ41 = *(const float4*)&rQL[1][lane*4];
  #pragma unroll
  for(int q=0;q<4;q++){
    int si = w*4+q;
    int s = st*16 + si;
    float4 dot0 = {0.f,0.f,0.f,0.f}, dot1 = {0.f,0.f,0.f,0.f};
    #pragma unroll
    for(int m=0;m<8;m++){
      float4 g4 = *(const float4*)(Gb + (size_t)m*65536 + s*256 + lane*4);
      dot0.x += aM0[m]*g4.x; dot0.y += aM0[m]*g4.y;
      dot0.z += aM0[m]*g4.z; dot0.w += aM0[m]*g4.w;
      dot1.x += aM1[m]*g4.x; dot1.y += aM1[m]*g4.y;
      dot1.z += aM1[m]*g4.z; dot1.w += aM1[m]*g4.w;
    }
    {
      float mKs = 512.f*mKL[0][s], rKs = rKL[0][s];
      float r0 = (dot0.x - mKs*mQ40.x)*rKs*rQ40.x*inv;
      float r1 = (dot0.y - mKs*mQ40.y)*rKs*rQ40.y*inv;
      float r2 = (dot0.z - mKs*mQ40.z)*rKs*rQ40.z*inv;
      float r3 = (dot0.w - mKs*mQ40.w)*rKs*rQ40.w*inv;
      float mx = wmax(fmaxf(fmaxf(r0,r1),fmaxf(r2,r3)));
      float e0=expf(r0-mx), e1=expf(r1-mx), e2=expf(r2-mx), e3=expf(r3-mx);
      float isf = 1.f/wsum(e0+e1+e2+e3);
      u16 pk[4] = {f2bf(e0*isf), f2bf(e1*isf), f2bf(e2*isf), f2bf(e3*isf)};
      *(ushort4*)(prB0 + ((si*512 + lane*8) ^ ((si&7)<<4))) = *(ushort4*)pk;
    }
    {
      float mKs = 512.f*mKL[1][s], rKs = rKL[1][s];
      float r0 = (dot1.x - mKs*mQ41.x)*rKs*rQ41.x*inv;
      float r1 = (dot1.y - mKs*mQ41.y)*rKs*rQ41.y*inv;
      float r2 = (dot1.z - mKs*mQ41.z)*rKs*rQ41.z*inv;
      float r3 = (dot1.w - mKs*mQ41.w)*rKs*rQ41.w*inv;
      float mx = wmax(fmaxf(fmaxf(r0,r1),fmaxf(r2,r3)));
      float e0=expf(r0-mx), e1=expf(r1-mx), e2=expf(r2-mx), e3=expf(r3-mx);
      float isf = 1.f/wsum(e0+e1+e2+e3);
      u16 pk[4] = {f2bf(e0*isf), f2bf(e1*isf), f2bf(e2*isf), f2bf(e3*isf)};
      *(ushort4*)(prB1 + ((si*512 + lane*8) ^ ((si&7)<<4))) = *(ushort4*)pk;
    }
  }
  __syncthreads();
  int m_ = lane&15, kb = lane>>4;
  f32x4 acc0 = {0.f,0.f,0.f,0.f}, acc1 = {0.f,0.f,0.f,0.f};
  const u16* xpB0 = xpB + (size_t)bj0*16384;
  const u16* xpB1 = xpB + (size_t)bj1*16384;
  #pragma unroll
  for(int ks=0;ks<8;ks++){
    int aoff = (m_*512 + ks*64 + kb*16) ^ ((m_&7)<<4);
    int boff = ((ks*4 + w)*64 + lane)*8;
    bf16x8 a0 = *(const bf16x8*)(prB0 + aoff);
    bf16x8 a1 = *(const bf16x8*)(prB1 + aoff);
    acc0 = __builtin_amdgcn_mfma_f32_16x16x32_bf16(a0, *(const bf16x8*)(xpB0 + boff), acc0, 0,0,0);
    acc1 = __builtin_amdgcn_mfma_f32_16x16x32_bf16(a1, *(const bf16x8*)(xpB1 + boff), acc1, 0,0,0);
  }
  __syncthreads();   // prB reads done; overlay xpT
  // stage xp window [2 j][3 rows][16 ci][64 f] (zero-padded rows), stride 68
  for(int idx4 = tid; idx4 < 1536; idx4 += 256){
    int jj = idx4 / 768;
    int rem = idx4 - jj*768;
    int rr_i = rem >> 8;
    int pos = rem & 255;
    int ci = pos>>4, f4 = pos&15;
    int grow = st - 1 + rr_i;
    float4 v = {0.f,0.f,0.f,0.f};
    if(grow>=0 && grow<16){
      v = *(const float4*)(xp + ((size_t)(b*16+j0+jj)*256 + grow*16 + ci)*64 + f4*4);
    }
    *(float4*)(xpT + ((jj*3+rr_i)*16+ci)*68 + f4*4) = v;
  }
  __syncthreads();
  int f = w*16 + m_;
  #pragma unroll
  for(int jj=0;jj<2;jj++){
    int j = j0+jj;
    int bj = b*16+j;
    f32x4 acc = jj ? acc1 : acc0;
    float al = fabsf(alpha[j]), be=fabsf(beta[j]), th=fabsf(theta[j]), ga=gamma_[j];
    const float* wq = cw + (j*64+f)*9;
    float w0=wq[0],w1=wq[1],w2=wq[2],w3v=wq[3],w4=wq[4],w5=wq[5],w6=wq[6],w7=wq[7],w8=wq[8];
    #pragma unroll
    for(int r=0;r<4;r++){
      int si = kb*4 + r;
      int s = st*16 + si;
      float gl = acc[r];
      float cv=0.f;
      #pragma unroll
      for(int dr=0;dr<3;dr++){
        float kw0 = dr==0?w0:(dr==1?w3v:w6);
        float kw1 = dr==0?w1:(dr==1?w4:w7);
        float kw2 = dr==0?w2:(dr==1?w5:w8);
        const float* rowp = xpT + ((jj*3+dr)*16)*68;
        if(si>0)  cv += rowp[(si-1)*68+f]*kw0;
                  cv += rowp[(si  )*68+f]*kw1;
        if(si<15) cv += rowp[(si+1)*68+f]*kw2;
      }
      float diag = xpT[((jj*3+1)*16+si)*68+f];
      size_t gi = ((size_t)bj*256+s)*64+f;
      out[gi] = be*gl + al*diag + th*cv + ga*xarr[gi];
    }
  }
}

extern "C" void kernel_launch(void* const* d_in, const int* in_sizes, int n_in,
                              void* d_out, int out_size, void* d_ws, size_t ws_size,
                              hipStream_t stream) {
  const float* xin = (const float*)d_in[0];
  const float* pxp = (const float*)d_in[1];
  const float* sw  = (const float*)d_in[2];
  const float* bs  = (const float*)d_in[3];
  const float* tau = (const float*)d_in[4];
  const float* temp= (const float*)d_in[5];
  const float* om  = (const float*)d_in[6];
  const float* W2  = (const float*)d_in[7];
  const float* bp  = (const float*)d_in[8];
  const float* lnw = (const float*)d_in[9];
  const float* lnb = (const float*)d_in[10];
  const float* alpha=(const float*)d_in[11];
  const float* beta= (const float*)d_in[12];
  const float* gam = (const float*)d_in[13];
  const float* theta=(const float*)d_in[14];
  const float* cw  = (const float*)d_in[15];
  float* outp = (float*)d_out;
  float* xpo  = outp + 2097152;   // x_prime = second output

  float* ws  = (float*)d_ws;
  float* xe  = ws;                // 32768
  float* xa  = xe + 32768;        // 32768
  float* Sv  = xa + 32768;        // 32768
  float* SSv = Sv + 32768;        // 32768
  float* er2 = SSv + 32768;       // 524288
  float* mask= er2 + 524288;      // 2048
  float* ccv = mask + 2048;       // 2048
  float* Gv  = ccv + 2048;        // 4194304
  float* xv  = Gv + 4194304;      // 2097152
  u16* xpB = (u16*)(xv + 2097152);    // 2097152 u16
  u16* w2B = xpB + 2097152;           // 65536 u16
  u16* xinb= w2B + 65536;             // 2097152 u16
  u16* phi = xinb + 2097152;          // 2097152 u16
  u16* plo = phi + 2097152;           // 2097152 u16

  kA<<<512,256,0,stream>>>(xin,pxp,W2,xe,xa,Sv,SSv,xinb,phi,plo,w2B);
  kBE<<<1152,256,0,stream>>>(xe,sw,bs,om,xa,tau,temp,er2,mask,ccv,phi,plo,Gv);
  kD<<<dim3(16,16,8),256,0,stream>>>(xinb,er2,mask,w2B,lnw,lnb,bp,xv,xpo,xpB);
  kF<<<dim3(8,16,8),256,0,stream>>>(Gv,ccv,Sv,SSv,xpo,xpB,cw,xv,temp,
                                    alpha,beta,gam,theta,outp);
}

// Round 7
// 66.032 us; speedup vs baseline: 2.9862x; 1.1407x over previous
//
#include <hip/hip_runtime.h>

#define EPSLN 1e-5f

typedef short bf16x8 __attribute__((ext_vector_type(8)));
typedef float f32x4 __attribute__((ext_vector_type(4)));
typedef unsigned short u16;
typedef unsigned short u16x8 __attribute__((ext_vector_type(8)));

__device__ __forceinline__ float wsum(float v){
  #pragma unroll
  for(int o=32;o;o>>=1) v += __shfl_xor(v,o);
  return v;
}
__device__ __forceinline__ float wmax(float v){
  #pragma unroll
  for(int o=32;o;o>>=1) v = fmaxf(v,__shfl_xor(v,o));
  return v;
}
__device__ __forceinline__ u16 f2bf(float f){
  unsigned int u = __float_as_uint(f);
  u = (u + 0x7FFFu + ((u>>16)&1u)) >> 16;
  return (u16)u;
}
__device__ __forceinline__ float bf2f(u16 h){
  return __uint_as_float(((unsigned int)h)<<16);
}

// A v2: quarter-row per thread. Stats via 2-shuffle 4-lane reduce.
// Blocks 0..15 also pack W2 into bf16 B-fragment order.
__global__ void __launch_bounds__(256) kA(
                   const float* __restrict__ xin, const float* __restrict__ p,
                   const float* __restrict__ W2,
                   float* __restrict__ xe, float* __restrict__ xa,
                   float* __restrict__ Sv, float* __restrict__ SSv,
                   u16* __restrict__ xinb, u16* __restrict__ phi, u16* __restrict__ plo,
                   u16* __restrict__ w2B){
  int t = threadIdx.x;
  int rl = t>>2, q = t&3;
  int row = blockIdx.x*64 + rl;
  const float4* xr = (const float4*)(xin + row*64 + q*16);
  const float4* pr = (const float4*)(p   + row*64 + q*16);
  float s1=0.f,s2=0.f,s3=0.f,s4=0.f;
  u16x8 xb[2], ph[2], pl[2];
  #pragma unroll
  for(int k=0;k<4;k++){
    float4 xv = xr[k];
    float4 pv = pr[k];
    s1 += xv.x+xv.y+xv.z+xv.w;
    s2 += fabsf(xv.x)+fabsf(xv.y)+fabsf(xv.z)+fabsf(xv.w);
    s3 += pv.x+pv.y+pv.z+pv.w;
    s4 += pv.x*pv.x+pv.y*pv.y+pv.z*pv.z+pv.w*pv.w;
    int h = k>>1, o = (k&1)*4;
    xb[h][o+0]=f2bf(xv.x); xb[h][o+1]=f2bf(xv.y);
    xb[h][o+2]=f2bf(xv.z); xb[h][o+3]=f2bf(xv.w);
    u16 h0=f2bf(pv.x), h1=f2bf(pv.y), h2=f2bf(pv.z), h3=f2bf(pv.w);
    ph[h][o+0]=h0; ph[h][o+1]=h1; ph[h][o+2]=h2; ph[h][o+3]=h3;
    pl[h][o+0]=f2bf(pv.x-bf2f(h0)); pl[h][o+1]=f2bf(pv.y-bf2f(h1));
    pl[h][o+2]=f2bf(pv.z-bf2f(h2)); pl[h][o+3]=f2bf(pv.w-bf2f(h3));
  }
  *(u16x8*)(xinb + row*64 + q*16    ) = xb[0];
  *(u16x8*)(xinb + row*64 + q*16 + 8) = xb[1];
  *(u16x8*)(phi  + row*64 + q*16    ) = ph[0];
  *(u16x8*)(phi  + row*64 + q*16 + 8) = ph[1];
  *(u16x8*)(plo  + row*64 + q*16    ) = pl[0];
  *(u16x8*)(plo  + row*64 + q*16 + 8) = pl[1];
  s1 += __shfl_xor(s1,1); s1 += __shfl_xor(s1,2);
  s2 += __shfl_xor(s2,1); s2 += __shfl_xor(s2,2);
  s3 += __shfl_xor(s3,1); s3 += __shfl_xor(s3,2);
  s4 += __shfl_xor(s4,1); s4 += __shfl_xor(s4,2);
  if(q==0){ xe[row]=s1*(1.f/64.f); xa[row]=s2*(1.f/64.f); Sv[row]=s3; SSv[row]=s4; }
  if(blockIdx.x<16){
    int j = blockIdx.x;
    for(int idx=threadIdx.x; idx<4096; idx+=256){
      int f = idx>>6, o = idx&63;
      float v = W2[j*4096 + idx];
      int ks = f>>5, kb = (f>>3)&3, i = f&7;
      int nt = o>>4, col = o&15;
      int ln = kb*16 + col;
      w2B[((j*2+ks)*4 + nt)*512 + ln*8 + i] = f2bf(v);
    }
  }
}

// BE: fused kB (blocks 0..127) + kE2 gram MFMA (blocks 128..1151). 32KB LDS union.
// E2 block decomposition puts b in the low 3 bits -> XCD = b (L2 locality).
__global__ void __launch_bounds__(256) kBE(
                   const float* __restrict__ xe, const float* __restrict__ sw,
                   const float* __restrict__ bs, const float* __restrict__ om,
                   const float* __restrict__ xa, const float* __restrict__ tau,
                   const float* __restrict__ temp,
                   float* __restrict__ er2, float* __restrict__ mask,
                   float* __restrict__ cc,
                   const u16* __restrict__ phi, const u16* __restrict__ plo,
                   float* __restrict__ G){
  __shared__ __align__(16) unsigned char shm[32768];
  int tid = threadIdx.x;
  if(blockIdx.x < 128){
    // ---- kB body ----
    float* swL = (float*)shm;          // 1072
    float* bsL = swL + 1072;           // 16
    float* omL = bsL + 16;             // 16
    float* red = omL + 16;             // 4
    float* redE= red + 4;              // [16][4]
    int bi = blockIdx.x;
    int i = bi & 15;
    int w = tid>>6, lane = tid&63;
    for(int k=tid;k<16*67;k+=256) swL[k] = sw[i*16*67 + k];
    if(tid<16){ bsL[tid]=bs[i*16+tid]; omL[tid]=fabsf(om[i*16+tid]); }
    float v = xe[bi*256+tid];
    float m = wmax(fabsf(v));
    if(lane==0) red[w]=m;
    __syncthreads();
    m = fmaxf(fmaxf(red[0],red[1]),fmaxf(red[2],red[3]));
    float xn = v/(m+1e-8f);
    xn = fminf(fmaxf(xn,-0.99f),0.99f);
    float sil = xn/(1.f+expf(-xn));
    float vv = (xn+1.f)*33.f;
    int c0 = (int)floorf(vv)-1;
    float acc[16];
    #pragma unroll
    for(int j=0;j<16;j++) acc[j]=0.f;
    #pragma unroll
    for(int k=0;k<4;k++){
      int c = c0+k;
      if(c<0||c>66) continue;
      float d = fabsf(vv-(float)c);
      float bas = d<1.f ? (2.f/3.f - d*d + d*d*d*0.5f)
                : (d<2.f ? (2.f-d)*(2.f-d)*(2.f-d)*(1.f/6.f) : 0.f);
      #pragma unroll
      for(int j=0;j<16;j++) acc[j] += bas*swL[j*67+c];
    }
    float xav = xa[bi*256+tid];
    #pragma unroll
    for(int j=0;j<16;j++){
      float ev = sil*bsL[j] + acc[j] + omL[j];
      er2[(bi*16+j)*256+tid] = ev;
      float pe = wsum(fabsf(ev)*xav);
      if(lane==0) redE[j*4+w]=pe;
    }
    __syncthreads();
    if(tid<16){
      float e = (redE[tid*4+0]+redE[tid*4+1]+redE[tid*4+2]+redE[tid*4+3])*(1.f/256.f);
      float tv = fabsf(temp[0])+1e-4f;
      float ta = fabsf(tau[i*16+tid]);
      float mk = 1.f/(1.f+expf(-(e-ta)/tv));
      mask[bi*16+tid]=mk;
      cc[bi*16+tid]= e/(ta+1e-8f)*mk;
    }
  } else {
    // ---- kE2 body ----
    u16* AfB = (u16*)shm;           // [2][4][2][64][8] = 8192 u16
    u16* BfB = AfB + 8192;
    int e = blockIdx.x - 128;
    int b = e&7, m = (e>>3)&7, sx = (e>>6)&3, ty = e>>8;  // b lowest -> XCD=b
    int bm = b*8+m;
    int s0 = sx*64, t0 = ty*64;
    int row = tid>>2, dseg = tid&3;
    size_t offA = ((size_t)(b*16+m  )*256 + s0 + row)*64 + dseg*16;
    size_t offB = ((size_t)(b*16+m+8)*256 + t0 + row)*64 + dseg*16;
    int d0 = dseg*16;
    int ks0 = d0>>5, kb0 = (d0>>3)&3;
    int ks1 = (d0+8)>>5, kb1 = ((d0+8)>>3)&3;
    int lr = row&15, stile = row>>4;
    #define AOFF(h,stl,ks,ln) (((((h)*4+(stl))*2+(ks))*64 + (ln))*8)
    {
      uint4 v0 = *(const uint4*)(phi + offA);
      uint4 v1 = *(const uint4*)(phi + offA + 8);
      *(uint4*)(AfB + AOFF(0,stile,ks0,kb0*16+lr)) = v0;
      *(uint4*)(AfB + AOFF(0,stile,ks1,kb1*16+lr)) = v1;
      uint4 w0 = *(const uint4*)(plo + offA);
      uint4 w1 = *(const uint4*)(plo + offA + 8);
      *(uint4*)(AfB + AOFF(1,stile,ks0,kb0*16+lr)) = w0;
      *(uint4*)(AfB + AOFF(1,stile,ks1,kb1*16+lr)) = w1;
      uint4 x0 = *(const uint4*)(phi + offB);
      uint4 x1 = *(const uint4*)(phi + offB + 8);
      *(uint4*)(BfB + AOFF(0,stile,ks0,kb0*16+lr)) = x0;
      *(uint4*)(BfB + AOFF(0,stile,ks1,kb1*16+lr)) = x1;
      uint4 y0 = *(const uint4*)(plo + offB);
      uint4 y1 = *(const uint4*)(plo + offB + 8);
      *(uint4*)(BfB + AOFF(1,stile,ks0,kb0*16+lr)) = y0;
      *(uint4*)(BfB + AOFF(1,stile,ks1,kb1*16+lr)) = y1;
    }
    __syncthreads();
    int w = tid>>6, lane = tid&63;
    bf16x8 ah0 = *(const bf16x8*)(AfB + AOFF(0,w,0,lane));
    bf16x8 ah1 = *(const bf16x8*)(AfB + AOFF(0,w,1,lane));
    bf16x8 al0 = *(const bf16x8*)(AfB + AOFF(1,w,0,lane));
    bf16x8 al1 = *(const bf16x8*)(AfB + AOFF(1,w,1,lane));
    f32x4 acc[4];
    #pragma unroll
    for(int tt=0;tt<4;tt++) acc[tt] = (f32x4){0.f,0.f,0.f,0.f};
    #pragma unroll
    for(int tt=0;tt<4;tt++){
      bf16x8 bh0 = *(const bf16x8*)(BfB + AOFF(0,tt,0,lane));
      bf16x8 bh1 = *(const bf16x8*)(BfB + AOFF(0,tt,1,lane));
      bf16x8 bl0 = *(const bf16x8*)(BfB + AOFF(1,tt,0,lane));
      bf16x8 bl1 = *(const bf16x8*)(BfB + AOFF(1,tt,1,lane));
      acc[tt] = __builtin_amdgcn_mfma_f32_16x16x32_bf16(ah0, bh0, acc[tt], 0,0,0);
      acc[tt] = __builtin_amdgcn_mfma_f32_16x16x32_bf16(ah1, bh1, acc[tt], 0,0,0);
      acc[tt] = __builtin_amdgcn_mfma_f32_16x16x32_bf16(ah0, bl0, acc[tt], 0,0,0);
      acc[tt] = __builtin_amdgcn_mfma_f32_16x16x32_bf16(ah1, bl1, acc[tt], 0,0,0);
      acc[tt] = __builtin_amdgcn_mfma_f32_16x16x32_bf16(al0, bh0, acc[tt], 0,0,0);
      acc[tt] = __builtin_amdgcn_mfma_f32_16x16x32_bf16(al1, bh1, acc[tt], 0,0,0);
    }
    int col = lane&15, r4 = lane>>4;
    #pragma unroll
    for(int tt=0;tt<4;tt++){
      #pragma unroll
      for(int r=0;r<4;r++){
        G[((size_t)bm*256 + s0 + w*16 + r4*4 + r)*256 + t0 + tt*16 + col] = acc[tt][r];
      }
    }
    #undef AOFF
  }
}

// D: x = masked mean over i (bf16 xin); LN; x' = xn@W2[j] via MFMA; emit xpB
// b in blockIdx.x -> XCD=b (xinb/er2 L2-resident per XCD)
__global__ void __launch_bounds__(256) kD(
                   const u16* __restrict__ xinb, const float* __restrict__ er2,
                   const float* __restrict__ mask, const u16* __restrict__ w2B,
                   const float* __restrict__ lnw, const float* __restrict__ lnb,
                   const float* __restrict__ bp,
                   float* __restrict__ xout, float* __restrict__ xp,
                   u16* __restrict__ xpB){
  int b = blockIdx.x, j = blockIdx.y, st = blockIdx.z;
  int tid = threadIdx.x, w = tid>>6, lane = tid&63;
  __shared__ __align__(16) u16 xnS[16*64];  // bf16, XOR-swizzled
  __shared__ float mcL[16];
  if(tid<16) mcL[tid]=mask[(b*16+tid)*16+j];
  __syncthreads();
  float lw = lnw[j*64+lane], lb = lnb[j*64+lane];
  int bj = b*16+j;
  unsigned char* xnB = (unsigned char*)xnS;
  #pragma unroll
  for(int ri=0;ri<4;ri++){
    int sl = w*4 + ri;
    int s = st*16 + sl;
    float acc=0.f;
    #pragma unroll
    for(int i=0;i<16;i++){
      acc += er2[((b*16+i)*16+j)*256+s]*mcL[i]*bf2f(xinb[((b*16+i)*256+s)*64+lane]);
    }
    float xval = acc*(1.f/16.f);
    xout[((size_t)bj*256+s)*64+lane]=xval;
    float mu = wsum(xval)*(1.f/64.f);
    float dv = xval-mu;
    float var = wsum(dv*dv)*(1.f/64.f);
    float xnv = dv*rsqrtf(var+EPSLN)*lw + lb;
    *(u16*)(xnB + ((sl*128 + lane*2) ^ ((sl&7)<<4))) = f2bf(xnv);
  }
  __syncthreads();
  f32x4 acc = {0.f,0.f,0.f,0.f};
  int m = lane&15, kb = lane>>4;
  #pragma unroll
  for(int ks=0;ks<2;ks++){
    bf16x8 a = *(const bf16x8*)(xnB + ((m*128 + ks*64 + kb*16) ^ ((m&7)<<4)));
    bf16x8 bfr = *(const bf16x8*)(w2B + ((j*2+ks)*4 + w)*512 + lane*8);
    acc = __builtin_amdgcn_mfma_f32_16x16x32_bf16(a, bfr, acc, 0, 0, 0);
  }
  int f = w*16 + m;
  u16 pk[4];
  #pragma unroll
  for(int r=0;r<4;r++){
    int si = kb*4 + r;
    int s = st*16 + si;
    float xpr = acc[r] + bp[((size_t)j*256+s)*64+f];
    xp[((size_t)bj*256+s)*64+f] = xpr;
    pk[r] = f2bf(xpr);
  }
  int s0 = st*16 + kb*4;
  int flat = ((s0>>5)*4 + w)*512 + ((s0>>3)&3)*128 + m*8 + (s0&7);
  *(ushort4*)(xpB + (size_t)bj*16384 + flat) = *(ushort4*)pk;
}

// F: 2 j per block; inline LN stats; logits -> softmax -> MFMA AV;
//    conv via LDS-staged xp window; residuals. b in blockIdx.x -> XCD=b
//    (each XCD keeps its b's 2MB of G in L2).
__global__ void __launch_bounds__(256) kF(
    const float* __restrict__ G, const float* __restrict__ cc,
    const float* __restrict__ Sv, const float* __restrict__ SSv,
    const float* __restrict__ xp, const u16* __restrict__ xpB,
    const float* __restrict__ cw,
    const float* __restrict__ xarr, const float* __restrict__ temp,
    const float* __restrict__ alpha, const float* __restrict__ beta,
    const float* __restrict__ gamma_, const float* __restrict__ theta,
    float* __restrict__ out){
  int b = blockIdx.x, jp = blockIdx.y, st = blockIdx.z;
  int j0 = jp*2, j1 = j0+1;
  int tid = threadIdx.x, w = tid>>6, lane = tid&63;
  __shared__ __align__(16) unsigned char ovl[26112];     // probS (16KB) / xpT (25.5KB)
  __shared__ float mKL[2][256], rKL[2][256];
  __shared__ __align__(16) float mQL[2][256], rQL[2][256];
  unsigned char* prB0 = ovl;
  unsigned char* prB1 = ovl + 8192;
  float* xpT = (float*)ovl;                              // [2][3][16][68]
  float tv = fabsf(temp[0])+1e-4f;
  float inv = 1.f/(sqrtf(512.f)*tv);
  float ck0[8],cq0[8],ck1[8],cq1[8],aM0[8],aM1[8];
  #pragma unroll
  for(int m=0;m<8;m++){
    ck0[m]=cc[(b*16+m)*16+j0];  cq0[m]=cc[(b*16+m+8)*16+j0];
    ck1[m]=cc[(b*16+m)*16+j1];  cq1[m]=cc[(b*16+m+8)*16+j1];
    aM0[m]=ck0[m]*cq0[m];       aM1[m]=ck1[m]*cq1[m];
  }
  {
    int t = tid;
    float sk0=0,ssk0=0,sq0=0,ssq0=0,sk1=0,ssk1=0,sq1=0,ssq1=0;
    #pragma unroll
    for(int m=0;m<8;m++){
      float svk = Sv [(b*16+m)*256+t];
      float ssvk= SSv[(b*16+m)*256+t];
      float svq = Sv [(b*16+m+8)*256+t];
      float ssvq= SSv[(b*16+m+8)*256+t];
      sk0 += ck0[m]*svk;  ssk0 += ck0[m]*ck0[m]*ssvk;
      sq0 += cq0[m]*svq;  ssq0 += cq0[m]*cq0[m]*ssvq;
      sk1 += ck1[m]*svk;  ssk1 += ck1[m]*ck1[m]*ssvk;
      sq1 += cq1[m]*svq;  ssq1 += cq1[m]*cq1[m]*ssvq;
    }
    float mk0 = sk0*(1.f/512.f), mk1 = sk1*(1.f/512.f);
    float mq0 = sq0*(1.f/512.f), mq1 = sq1*(1.f/512.f);
    mKL[0][t]=mk0; rKL[0][t]=rsqrtf(ssk0*(1.f/512.f)-mk0*mk0+EPSLN);
    mKL[1][t]=mk1; rKL[1][t]=rsqrtf(ssk1*(1.f/512.f)-mk1*mk1+EPSLN);
    mQL[0][t]=mq0; rQL[0][t]=rsqrtf(ssq0*(1.f/512.f)-mq0*mq0+EPSLN);
    mQL[1][t]=mq1; rQL[1][t]=rsqrtf(ssq1*(1.f/512.f)-mq1*mq1+EPSLN);
  }
  __syncthreads();
  int bj0 = b*16+j0, bj1 = b*16+j1;
  const float* Gb = G + (size_t)(b*8)*65536;
  float4 mQ40 = *(const float4*)&mQL[0][lane*4];
  float4 rQ40 = *(const float4*)&rQL[0][lane*4];
  float4 mQ41 = *(const float4*)&mQL[1][lane*4];
  float4 rQ41 = *(const float4*)&rQL[1][lane*4];
  #pragma unroll
  for(int q=0;q<4;q++){
    int si = w*4+q;
    int s = st*16 + si;
    float4 dot0 = {0.f,0.f,0.f,0.f}, dot1 = {0.f,0.f,0.f,0.f};
    #pragma unroll
    for(int m=0;m<8;m++){
      float4 g4 = *(const float4*)(Gb + (size_t)m*65536 + s*256 + lane*4);
      dot0.x += aM0[m]*g4.x; dot0.y += aM0[m]*g4.y;
      dot0.z += aM0[m]*g4.z; dot0.w += aM0[m]*g4.w;
      dot1.x += aM1[m]*g4.x; dot1.y += aM1[m]*g4.y;
      dot1.z += aM1[m]*g4.z; dot1.w += aM1[m]*g4.w;
    }
    {
      float mKs = 512.f*mKL[0][s], rKs = rKL[0][s];
      float r0 = (dot0.x - mKs*mQ40.x)*rKs*rQ40.x*inv;
      float r1 = (dot0.y - mKs*mQ40.y)*rKs*rQ40.y*inv;
      float r2 = (dot0.z - mKs*mQ40.z)*rKs*rQ40.z*inv;
      float r3 = (dot0.w - mKs*mQ40.w)*rKs*rQ40.w*inv;
      float mx = wmax(fmaxf(fmaxf(r0,r1),fmaxf(r2,r3)));
      float e0=expf(r0-mx), e1=expf(r1-mx), e2=expf(r2-mx), e3=expf(r3-mx);
      float isf = 1.f/wsum(e0+e1+e2+e3);
      u16 pk[4] = {f2bf(e0*isf), f2bf(e1*isf), f2bf(e2*isf), f2bf(e3*isf)};
      *(ushort4*)(prB0 + ((si*512 + lane*8) ^ ((si&7)<<4))) = *(ushort4*)pk;
    }
    {
      float mKs = 512.f*mKL[1][s], rKs = rKL[1][s];
      float r0 = (dot1.x - mKs*mQ41.x)*rKs*rQ41.x*inv;
      float r1 = (dot1.y - mKs*mQ41.y)*rKs*rQ41.y*inv;
      float r2 = (dot1.z - mKs*mQ41.z)*rKs*rQ41.z*inv;
      float r3 = (dot1.w - mKs*mQ41.w)*rKs*rQ41.w*inv;
      float mx = wmax(fmaxf(fmaxf(r0,r1),fmaxf(r2,r3)));
      float e0=expf(r0-mx), e1=expf(r1-mx), e2=expf(r2-mx), e3=expf(r3-mx);
      float isf = 1.f/wsum(e0+e1+e2+e3);
      u16 pk[4] = {f2bf(e0*isf), f2bf(e1*isf), f2bf(e2*isf), f2bf(e3*isf)};
      *(ushort4*)(prB1 + ((si*512 + lane*8) ^ ((si&7)<<4))) = *(ushort4*)pk;
    }
  }
  __syncthreads();
  int m_ = lane&15, kb = lane>>4;
  f32x4 acc0 = {0.f,0.f,0.f,0.f}, acc1 = {0.f,0.f,0.f,0.f};
  const u16* xpB0 = xpB + (size_t)bj0*16384;
  const u16* xpB1 = xpB + (size_t)bj1*16384;
  #pragma unroll
  for(int ks=0;ks<8;ks++){
    int aoff = (m_*512 + ks*64 + kb*16) ^ ((m_&7)<<4);
    int boff = ((ks*4 + w)*64 + lane)*8;
    bf16x8 a0 = *(const bf16x8*)(prB0 + aoff);
    bf16x8 a1 = *(const bf16x8*)(prB1 + aoff);
    acc0 = __builtin_amdgcn_mfma_f32_16x16x32_bf16(a0, *(const bf16x8*)(xpB0 + boff), acc0, 0,0,0);
    acc1 = __builtin_amdgcn_mfma_f32_16x16x32_bf16(a1, *(const bf16x8*)(xpB1 + boff), acc1, 0,0,0);
  }
  __syncthreads();   // prB reads done; overlay xpT
  // stage xp window [2 j][3 rows][16 ci][64 f] (zero-padded rows), stride 68
  for(int idx4 = tid; idx4 < 1536; idx4 += 256){
    int jj = idx4 / 768;
    int rem = idx4 - jj*768;
    int rr_i = rem >> 8;
    int pos = rem & 255;
    int ci = pos>>4, f4 = pos&15;
    int grow = st - 1 + rr_i;
    float4 v = {0.f,0.f,0.f,0.f};
    if(grow>=0 && grow<16){
      v = *(const float4*)(xp + ((size_t)(b*16+j0+jj)*256 + grow*16 + ci)*64 + f4*4);
    }
    *(float4*)(xpT + ((jj*3+rr_i)*16+ci)*68 + f4*4) = v;
  }
  __syncthreads();
  int f = w*16 + m_;
  #pragma unroll
  for(int jj=0;jj<2;jj++){
    int j = j0+jj;
    int bj = b*16+j;
    f32x4 acc = jj ? acc1 : acc0;
    float al = fabsf(alpha[j]), be=fabsf(beta[j]), th=fabsf(theta[j]), ga=gamma_[j];
    const float* wq = cw + (j*64+f)*9;
    float w0=wq[0],w1=wq[1],w2=wq[2],w3v=wq[3],w4=wq[4],w5=wq[5],w6=wq[6],w7=wq[7],w8=wq[8];
    #pragma unroll
    for(int r=0;r<4;r++){
      int si = kb*4 + r;
      int s = st*16 + si;
      float gl = acc[r];
      float cv=0.f;
      #pragma unroll
      for(int dr=0;dr<3;dr++){
        float kw0 = dr==0?w0:(dr==1?w3v:w6);
        float kw1 = dr==0?w1:(dr==1?w4:w7);
        float kw2 = dr==0?w2:(dr==1?w5:w8);
        const float* rowp = xpT + ((jj*3+dr)*16)*68;
        if(si>0)  cv += rowp[(si-1)*68+f]*kw0;
                  cv += rowp[(si  )*68+f]*kw1;
        if(si<15) cv += rowp[(si+1)*68+f]*kw2;
      }
      float diag = xpT[((jj*3+1)*16+si)*68+f];
      size_t gi = ((size_t)bj*256+s)*64+f;
      out[gi] = be*gl + al*diag + th*cv + ga*xarr[gi];
    }
  }
}

extern "C" void kernel_launch(void* const* d_in, const int* in_sizes, int n_in,
                              void* d_out, int out_size, void* d_ws, size_t ws_size,
                              hipStream_t stream) {
  const float* xin = (const float*)d_in[0];
  const float* pxp = (const float*)d_in[1];
  const float* sw  = (const float*)d_in[2];
  const float* bs  = (const float*)d_in[3];
  const float* tau = (const float*)d_in[4];
  const float* temp= (const float*)d_in[5];
  const float* om  = (const float*)d_in[6];
  const float* W2  = (const float*)d_in[7];
  const float* bp  = (const float*)d_in[8];
  const float* lnw = (const float*)d_in[9];
  const float* lnb = (const float*)d_in[10];
  const float* alpha=(const float*)d_in[11];
  const float* beta= (const float*)d_in[12];
  const float* gam = (const float*)d_in[13];
  const float* theta=(const float*)d_in[14];
  const float* cw  = (const float*)d_in[15];
  float* outp = (float*)d_out;
  float* xpo  = outp + 2097152;   // x_prime = second output

  float* ws  = (float*)d_ws;
  float* xe  = ws;                // 32768
  float* xa  = xe + 32768;        // 32768
  float* Sv  = xa + 32768;        // 32768
  float* SSv = Sv + 32768;        // 32768
  float* er2 = SSv + 32768;       // 524288
  float* mask= er2 + 524288;      // 2048
  float* ccv = mask + 2048;       // 2048
  float* Gv  = ccv + 2048;        // 4194304
  float* xv  = Gv + 4194304;      // 2097152
  u16* xpB = (u16*)(xv + 2097152);    // 2097152 u16
  u16* w2B = xpB + 2097152;           // 65536 u16
  u16* xinb= w2B + 65536;             // 2097152 u16
  u16* phi = xinb + 2097152;          // 2097152 u16
  u16* plo = phi + 2097152;           // 2097152 u16

  kA<<<512,256,0,stream>>>(xin,pxp,W2,xe,xa,Sv,SSv,xinb,phi,plo,w2B);
  kBE<<<1152,256,0,stream>>>(xe,sw,bs,om,xa,tau,temp,er2,mask,ccv,phi,plo,Gv);
  kD<<<dim3(8,16,16),256,0,stream>>>(xinb,er2,mask,w2B,lnw,lnb,bp,xv,xpo,xpB);
  kF<<<dim3(8,8,16),256,0,stream>>>(Gv,ccv,Sv,SSv,xpo,xpB,cw,xv,temp,
                                    alpha,beta,gam,theta,outp);
}

// Round 8
// 63.016 us; speedup vs baseline: 3.1291x; 1.0479x over previous
//
#include <hip/hip_runtime.h>

#define EPSLN 1e-5f

typedef short bf16x8 __attribute__((ext_vector_type(8)));
typedef float f32x4 __attribute__((ext_vector_type(4)));
typedef unsigned short u16;
typedef unsigned short u16x8 __attribute__((ext_vector_type(8)));

__device__ __forceinline__ float wsum(float v){
  #pragma unroll
  for(int o=32;o;o>>=1) v += __shfl_xor(v,o);
  return v;
}
__device__ __forceinline__ float wmax(float v){
  #pragma unroll
  for(int o=32;o;o>>=1) v = fmaxf(v,__shfl_xor(v,o));
  return v;
}
__device__ __forceinline__ u16 f2bf(float f){
  unsigned int u = __float_as_uint(f);
  u = (u + 0x7FFFu + ((u>>16)&1u)) >> 16;
  return (u16)u;
}
__device__ __forceinline__ float bf2f(u16 h){
  return __uint_as_float(((unsigned int)h)<<16);
}

// A v3: eighth-row per thread (8 floats), 4 blocks/CU occupancy.
// Blocks 0..15 also pack W2 into bf16 B-fragment order.
__global__ void __launch_bounds__(256) kA(
                   const float* __restrict__ xin, const float* __restrict__ p,
                   const float* __restrict__ W2,
                   float* __restrict__ xe, float* __restrict__ xa,
                   float* __restrict__ Sv, float* __restrict__ SSv,
                   u16* __restrict__ xinb, u16* __restrict__ phi, u16* __restrict__ plo,
                   u16* __restrict__ w2B){
  int t = threadIdx.x;
  int rl = t>>3, q = t&7;
  int row = blockIdx.x*32 + rl;
  const float4* xr = (const float4*)(xin + row*64 + q*8);
  const float4* pr = (const float4*)(p   + row*64 + q*8);
  float s1=0.f,s2=0.f,s3=0.f,s4=0.f;
  u16x8 xb, ph, pl;
  #pragma unroll
  for(int k=0;k<2;k++){
    float4 xv = xr[k];
    float4 pv = pr[k];
    s1 += xv.x+xv.y+xv.z+xv.w;
    s2 += fabsf(xv.x)+fabsf(xv.y)+fabsf(xv.z)+fabsf(xv.w);
    s3 += pv.x+pv.y+pv.z+pv.w;
    s4 += pv.x*pv.x+pv.y*pv.y+pv.z*pv.z+pv.w*pv.w;
    int o = k*4;
    xb[o+0]=f2bf(xv.x); xb[o+1]=f2bf(xv.y); xb[o+2]=f2bf(xv.z); xb[o+3]=f2bf(xv.w);
    u16 h0=f2bf(pv.x), h1=f2bf(pv.y), h2=f2bf(pv.z), h3=f2bf(pv.w);
    ph[o+0]=h0; ph[o+1]=h1; ph[o+2]=h2; ph[o+3]=h3;
    pl[o+0]=f2bf(pv.x-bf2f(h0)); pl[o+1]=f2bf(pv.y-bf2f(h1));
    pl[o+2]=f2bf(pv.z-bf2f(h2)); pl[o+3]=f2bf(pv.w-bf2f(h3));
  }
  *(u16x8*)(xinb + row*64 + q*8) = xb;
  *(u16x8*)(phi  + row*64 + q*8) = ph;
  *(u16x8*)(plo  + row*64 + q*8) = pl;
  s1 += __shfl_xor(s1,1); s1 += __shfl_xor(s1,2); s1 += __shfl_xor(s1,4);
  s2 += __shfl_xor(s2,1); s2 += __shfl_xor(s2,2); s2 += __shfl_xor(s2,4);
  s3 += __shfl_xor(s3,1); s3 += __shfl_xor(s3,2); s3 += __shfl_xor(s3,4);
  s4 += __shfl_xor(s4,1); s4 += __shfl_xor(s4,2); s4 += __shfl_xor(s4,4);
  if(q==0){ xe[row]=s1*(1.f/64.f); xa[row]=s2*(1.f/64.f); Sv[row]=s3; SSv[row]=s4; }
  if(blockIdx.x<16){
    int j = blockIdx.x;
    for(int idx=threadIdx.x; idx<4096; idx+=256){
      int f = idx>>6, o = idx&63;
      float v = W2[j*4096 + idx];
      int ks = f>>5, kb = (f>>3)&3, i = f&7;
      int nt = o>>4, col = o&15;
      int ln = kb*16 + col;
      w2B[((j*2+ks)*4 + nt)*512 + ln*8 + i] = f2bf(v);
    }
  }
}

// BE: fused kB (blocks 0..127) + kE2 gram MFMA (blocks 128..1151). 32KB LDS union.
// E2 decomposition has b in low 3 bits -> XCD = b (L2 locality).
__global__ void __launch_bounds__(256) kBE(
                   const float* __restrict__ xe, const float* __restrict__ sw,
                   const float* __restrict__ bs, const float* __restrict__ om,
                   const float* __restrict__ xa, const float* __restrict__ tau,
                   const float* __restrict__ temp,
                   float* __restrict__ er2, float* __restrict__ mask,
                   float* __restrict__ cc,
                   const u16* __restrict__ phi, const u16* __restrict__ plo,
                   float* __restrict__ G){
  __shared__ __align__(16) unsigned char shm[32768];
  int tid = threadIdx.x;
  if(blockIdx.x < 128){
    // ---- kB body ----
    float* swL = (float*)shm;          // 1072
    float* bsL = swL + 1072;           // 16
    float* omL = bsL + 16;             // 16
    float* red = omL + 16;             // 4
    float* redE= red + 4;              // [16][4]
    int bi = blockIdx.x;
    int i = bi & 15;
    int w = tid>>6, lane = tid&63;
    for(int k=tid;k<16*67;k+=256) swL[k] = sw[i*16*67 + k];
    if(tid<16){ bsL[tid]=bs[i*16+tid]; omL[tid]=fabsf(om[i*16+tid]); }
    float v = xe[bi*256+tid];
    float m = wmax(fabsf(v));
    if(lane==0) red[w]=m;
    __syncthreads();
    m = fmaxf(fmaxf(red[0],red[1]),fmaxf(red[2],red[3]));
    float xn = v/(m+1e-8f);
    xn = fminf(fmaxf(xn,-0.99f),0.99f);
    float sil = xn/(1.f+expf(-xn));
    float vv = (xn+1.f)*33.f;
    int c0 = (int)floorf(vv)-1;
    float acc[16];
    #pragma unroll
    for(int j=0;j<16;j++) acc[j]=0.f;
    #pragma unroll
    for(int k=0;k<4;k++){
      int c = c0+k;
      if(c<0||c>66) continue;
      float d = fabsf(vv-(float)c);
      float bas = d<1.f ? (2.f/3.f - d*d + d*d*d*0.5f)
                : (d<2.f ? (2.f-d)*(2.f-d)*(2.f-d)*(1.f/6.f) : 0.f);
      #pragma unroll
      for(int j=0;j<16;j++) acc[j] += bas*swL[j*67+c];
    }
    float xav = xa[bi*256+tid];
    #pragma unroll
    for(int j=0;j<16;j++){
      float ev = sil*bsL[j] + acc[j] + omL[j];
      er2[(bi*16+j)*256+tid] = ev;
      float pe = wsum(fabsf(ev)*xav);
      if(lane==0) redE[j*4+w]=pe;
    }
    __syncthreads();
    if(tid<16){
      float e = (redE[tid*4+0]+redE[tid*4+1]+redE[tid*4+2]+redE[tid*4+3])*(1.f/256.f);
      float tv = fabsf(temp[0])+1e-4f;
      float ta = fabsf(tau[i*16+tid]);
      float mk = 1.f/(1.f+expf(-(e-ta)/tv));
      mask[bi*16+tid]=mk;
      cc[bi*16+tid]= e/(ta+1e-8f)*mk;
    }
  } else {
    // ---- kE2 body ----
    u16* AfB = (u16*)shm;           // [2][4][2][64][8] = 8192 u16
    u16* BfB = AfB + 8192;
    int e = blockIdx.x - 128;
    int b = e&7, m = (e>>3)&7, sx = (e>>6)&3, ty = e>>8;  // b lowest -> XCD=b
    int bm = b*8+m;
    int s0 = sx*64, t0 = ty*64;
    int row = tid>>2, dseg = tid&3;
    size_t offA = ((size_t)(b*16+m  )*256 + s0 + row)*64 + dseg*16;
    size_t offB = ((size_t)(b*16+m+8)*256 + t0 + row)*64 + dseg*16;
    int d0 = dseg*16;
    int ks0 = d0>>5, kb0 = (d0>>3)&3;
    int ks1 = (d0+8)>>5, kb1 = ((d0+8)>>3)&3;
    int lr = row&15, stile = row>>4;
    #define AOFF(h,stl,ks,ln) (((((h)*4+(stl))*2+(ks))*64 + (ln))*8)
    {
      uint4 v0 = *(const uint4*)(phi + offA);
      uint4 v1 = *(const uint4*)(phi + offA + 8);
      *(uint4*)(AfB + AOFF(0,stile,ks0,kb0*16+lr)) = v0;
      *(uint4*)(AfB + AOFF(0,stile,ks1,kb1*16+lr)) = v1;
      uint4 w0 = *(const uint4*)(plo + offA);
      uint4 w1 = *(const uint4*)(plo + offA + 8);
      *(uint4*)(AfB + AOFF(1,stile,ks0,kb0*16+lr)) = w0;
      *(uint4*)(AfB + AOFF(1,stile,ks1,kb1*16+lr)) = w1;
      uint4 x0 = *(const uint4*)(phi + offB);
      uint4 x1 = *(const uint4*)(phi + offB + 8);
      *(uint4*)(BfB + AOFF(0,stile,ks0,kb0*16+lr)) = x0;
      *(uint4*)(BfB + AOFF(0,stile,ks1,kb1*16+lr)) = x1;
      uint4 y0 = *(const uint4*)(plo + offB);
      uint4 y1 = *(const uint4*)(plo + offB + 8);
      *(uint4*)(BfB + AOFF(1,stile,ks0,kb0*16+lr)) = y0;
      *(uint4*)(BfB + AOFF(1,stile,ks1,kb1*16+lr)) = y1;
    }
    __syncthreads();
    int w = tid>>6, lane = tid&63;
    bf16x8 ah0 = *(const bf16x8*)(AfB + AOFF(0,w,0,lane));
    bf16x8 ah1 = *(const bf16x8*)(AfB + AOFF(0,w,1,lane));
    bf16x8 al0 = *(const bf16x8*)(AfB + AOFF(1,w,0,lane));
    bf16x8 al1 = *(const bf16x8*)(AfB + AOFF(1,w,1,lane));
    f32x4 acc[4];
    #pragma unroll
    for(int tt=0;tt<4;tt++) acc[tt] = (f32x4){0.f,0.f,0.f,0.f};
    #pragma unroll
    for(int tt=0;tt<4;tt++){
      bf16x8 bh0 = *(const bf16x8*)(BfB + AOFF(0,tt,0,lane));
      bf16x8 bh1 = *(const bf16x8*)(BfB + AOFF(0,tt,1,lane));
      bf16x8 bl0 = *(const bf16x8*)(BfB + AOFF(1,tt,0,lane));
      bf16x8 bl1 = *(const bf16x8*)(BfB + AOFF(1,tt,1,lane));
      acc[tt] = __builtin_amdgcn_mfma_f32_16x16x32_bf16(ah0, bh0, acc[tt], 0,0,0);
      acc[tt] = __builtin_amdgcn_mfma_f32_16x16x32_bf16(ah1, bh1, acc[tt], 0,0,0);
      acc[tt] = __builtin_amdgcn_mfma_f32_16x16x32_bf16(ah0, bl0, acc[tt], 0,0,0);
      acc[tt] = __builtin_amdgcn_mfma_f32_16x16x32_bf16(ah1, bl1, acc[tt], 0,0,0);
      acc[tt] = __builtin_amdgcn_mfma_f32_16x16x32_bf16(al0, bh0, acc[tt], 0,0,0);
      acc[tt] = __builtin_amdgcn_mfma_f32_16x16x32_bf16(al1, bh1, acc[tt], 0,0,0);
    }
    int col = lane&15, r4 = lane>>4;
    #pragma unroll
    for(int tt=0;tt<4;tt++){
      #pragma unroll
      for(int r=0;r<4;r++){
        G[((size_t)bm*256 + s0 + w*16 + r4*4 + r)*256 + t0 + tt*16 + col] = acc[tt][r];
      }
    }
    #undef AOFF
  }
}

// D: x = masked mean over i (bf16 xin); LN; x' = xn@W2[j] via MFMA; emit xpB.
// xout now bf16. b in blockIdx.x -> XCD=b.
__global__ void __launch_bounds__(256) kD(
                   const u16* __restrict__ xinb, const float* __restrict__ er2,
                   const float* __restrict__ mask, const u16* __restrict__ w2B,
                   const float* __restrict__ lnw, const float* __restrict__ lnb,
                   const float* __restrict__ bp,
                   u16* __restrict__ xoutb, float* __restrict__ xp,
                   u16* __restrict__ xpB){
  int b = blockIdx.x, j = blockIdx.y, st = blockIdx.z;
  int tid = threadIdx.x, w = tid>>6, lane = tid&63;
  __shared__ __align__(16) u16 xnS[16*64];  // bf16, XOR-swizzled
  __shared__ float mcL[16];
  if(tid<16) mcL[tid]=mask[(b*16+tid)*16+j];
  __syncthreads();
  float lw = lnw[j*64+lane], lb = lnb[j*64+lane];
  int bj = b*16+j;
  unsigned char* xnB = (unsigned char*)xnS;
  #pragma unroll
  for(int ri=0;ri<4;ri++){
    int sl = w*4 + ri;
    int s = st*16 + sl;
    float acc=0.f;
    #pragma unroll
    for(int i=0;i<16;i++){
      acc += er2[((b*16+i)*16+j)*256+s]*mcL[i]*bf2f(xinb[((b*16+i)*256+s)*64+lane]);
    }
    float xval = acc*(1.f/16.f);
    xoutb[((size_t)bj*256+s)*64+lane]=f2bf(xval);
    float mu = wsum(xval)*(1.f/64.f);
    float dv = xval-mu;
    float var = wsum(dv*dv)*(1.f/64.f);
    float xnv = dv*rsqrtf(var+EPSLN)*lw + lb;
    *(u16*)(xnB + ((sl*128 + lane*2) ^ ((sl&7)<<4))) = f2bf(xnv);
  }
  __syncthreads();
  f32x4 acc = {0.f,0.f,0.f,0.f};
  int m = lane&15, kb = lane>>4;
  #pragma unroll
  for(int ks=0;ks<2;ks++){
    bf16x8 a = *(const bf16x8*)(xnB + ((m*128 + ks*64 + kb*16) ^ ((m&7)<<4)));
    bf16x8 bfr = *(const bf16x8*)(w2B + ((j*2+ks)*4 + w)*512 + lane*8);
    acc = __builtin_amdgcn_mfma_f32_16x16x32_bf16(a, bfr, acc, 0, 0, 0);
  }
  int f = w*16 + m;
  u16 pk[4];
  #pragma unroll
  for(int r=0;r<4;r++){
    int si = kb*4 + r;
    int s = st*16 + si;
    float xpr = acc[r] + bp[((size_t)j*256+s)*64+f];
    xp[((size_t)bj*256+s)*64+f] = xpr;
    pk[r] = f2bf(xpr);
  }
  int s0 = st*16 + kb*4;
  int flat = ((s0>>5)*4 + w)*512 + ((s0>>3)&3)*128 + m*8 + (s0&7);
  *(ushort4*)(xpB + (size_t)bj*16384 + flat) = *(ushort4*)pk;
}

// F: 2 j per block; inline LN stats; f32x4 (pk-fma) logit dot -> softmax ->
//    MFMA AV; conv via LDS-staged xp window; residuals. b in blockIdx.x -> XCD=b.
__global__ void __launch_bounds__(256) kF(
    const float* __restrict__ G, const float* __restrict__ cc,
    const float* __restrict__ Sv, const float* __restrict__ SSv,
    const float* __restrict__ xp, const u16* __restrict__ xpB,
    const float* __restrict__ cw,
    const u16* __restrict__ xarrb, const float* __restrict__ temp,
    const float* __restrict__ alpha, const float* __restrict__ beta,
    const float* __restrict__ gamma_, const float* __restrict__ theta,
    float* __restrict__ out){
  int b = blockIdx.x, jp = blockIdx.y, st = blockIdx.z;
  int j0 = jp*2, j1 = j0+1;
  int tid = threadIdx.x, w = tid>>6, lane = tid&63;
  __shared__ __align__(16) unsigned char ovl[26112];     // probS (16KB) / xpT (25.5KB)
  __shared__ float mKL[2][256], rKL[2][256];
  __shared__ __align__(16) float mQL[2][256], rQL[2][256];
  unsigned char* prB0 = ovl;
  unsigned char* prB1 = ovl + 8192;
  float* xpT = (float*)ovl;                              // [2][3][16][68]
  float tv = fabsf(temp[0])+1e-4f;
  float inv = 1.f/(sqrtf(512.f)*tv);
  float ck0[8],cq0[8],ck1[8],cq1[8],aM0[8],aM1[8];
  #pragma unroll
  for(int m=0;m<8;m++){
    ck0[m]=cc[(b*16+m)*16+j0];  cq0[m]=cc[(b*16+m+8)*16+j0];
    ck1[m]=cc[(b*16+m)*16+j1];  cq1[m]=cc[(b*16+m+8)*16+j1];
    aM0[m]=ck0[m]*cq0[m];       aM1[m]=ck1[m]*cq1[m];
  }
  {
    int t = tid;
    float sk0=0,ssk0=0,sq0=0,ssq0=0,sk1=0,ssk1=0,sq1=0,ssq1=0;
    #pragma unroll
    for(int m=0;m<8;m++){
      float svk = Sv [(b*16+m)*256+t];
      float ssvk= SSv[(b*16+m)*256+t];
      float svq = Sv [(b*16+m+8)*256+t];
      float ssvq= SSv[(b*16+m+8)*256+t];
      sk0 += ck0[m]*svk;  ssk0 += ck0[m]*ck0[m]*ssvk;
      sq0 += cq0[m]*svq;  ssq0 += cq0[m]*cq0[m]*ssvq;
      sk1 += ck1[m]*svk;  ssk1 += ck1[m]*ck1[m]*ssvk;
      sq1 += cq1[m]*svq;  ssq1 += cq1[m]*cq1[m]*ssvq;
    }
    float mk0 = sk0*(1.f/512.f), mk1 = sk1*(1.f/512.f);
    float mq0 = sq0*(1.f/512.f), mq1 = sq1*(1.f/512.f);
    mKL[0][t]=mk0; rKL[0][t]=rsqrtf(ssk0*(1.f/512.f)-mk0*mk0+EPSLN);
    mKL[1][t]=mk1; rKL[1][t]=rsqrtf(ssk1*(1.f/512.f)-mk1*mk1+EPSLN);
    mQL[0][t]=mq0; rQL[0][t]=rsqrtf(ssq0*(1.f/512.f)-mq0*mq0+EPSLN);
    mQL[1][t]=mq1; rQL[1][t]=rsqrtf(ssq1*(1.f/512.f)-mq1*mq1+EPSLN);
  }
  __syncthreads();
  int bj0 = b*16+j0, bj1 = b*16+j1;
  const float* Gb = G + (size_t)(b*8)*65536;
  float4 mQ40 = *(const float4*)&mQL[0][lane*4];
  float4 rQ40 = *(const float4*)&rQL[0][lane*4];
  float4 mQ41 = *(const float4*)&mQL[1][lane*4];
  float4 rQ41 = *(const float4*)&rQL[1][lane*4];
  #pragma unroll
  for(int q=0;q<4;q++){
    int si = w*4+q;
    int s = st*16 + si;
    f32x4 dot0 = {0.f,0.f,0.f,0.f}, dot1 = {0.f,0.f,0.f,0.f};
    #pragma unroll
    for(int m=0;m<8;m++){
      f32x4 g4 = *(const f32x4*)(Gb + (size_t)m*65536 + s*256 + lane*4);
      dot0 += aM0[m]*g4;     // vector op -> v_pk_fma_f32 pairs
      dot1 += aM1[m]*g4;
    }
    {
      float mKs = 512.f*mKL[0][s], rKs = rKL[0][s];
      float r0 = (dot0[0] - mKs*mQ40.x)*rKs*rQ40.x*inv;
      float r1 = (dot0[1] - mKs*mQ40.y)*rKs*rQ40.y*inv;
      float r2 = (dot0[2] - mKs*mQ40.z)*rKs*rQ40.z*inv;
      float r3 = (dot0[3] - mKs*mQ40.w)*rKs*rQ40.w*inv;
      float mx = wmax(fmaxf(fmaxf(r0,r1),fmaxf(r2,r3)));
      float e0=expf(r0-mx), e1=expf(r1-mx), e2=expf(r2-mx), e3=expf(r3-mx);
      float isf = 1.f/wsum(e0+e1+e2+e3);
      u16 pk[4] = {f2bf(e0*isf), f2bf(e1*isf), f2bf(e2*isf), f2bf(e3*isf)};
      *(ushort4*)(prB0 + ((si*512 + lane*8) ^ ((si&7)<<4))) = *(ushort4*)pk;
    }
    {
      float mKs = 512.f*mKL[1][s], rKs = rKL[1][s];
      float r0 = (dot1[0] - mKs*mQ41.x)*rKs*rQ41.x*inv;
      float r1 = (dot1[1] - mKs*mQ41.y)*rKs*rQ41.y*inv;
      float r2 = (dot1[2] - mKs*mQ41.z)*rKs*rQ41.z*inv;
      float r3 = (dot1[3] - mKs*mQ41.w)*rKs*rQ41.w*inv;
      float mx = wmax(fmaxf(fmaxf(r0,r1),fmaxf(r2,r3)));
      float e0=expf(r0-mx), e1=expf(r1-mx), e2=expf(r2-mx), e3=expf(r3-mx);
      float isf = 1.f/wsum(e0+e1+e2+e3);
      u16 pk[4] = {f2bf(e0*isf), f2bf(e1*isf), f2bf(e2*isf), f2bf(e3*isf)};
      *(ushort4*)(prB1 + ((si*512 + lane*8) ^ ((si&7)<<4))) = *(ushort4*)pk;
    }
  }
  __syncthreads();
  int m_ = lane&15, kb = lane>>4;
  f32x4 acc0 = {0.f,0.f,0.f,0.f}, acc1 = {0.f,0.f,0.f,0.f};
  const u16* xpB0 = xpB + (size_t)bj0*16384;
  const u16* xpB1 = xpB + (size_t)bj1*16384;
  #pragma unroll
  for(int ks=0;ks<8;ks++){
    int aoff = (m_*512 + ks*64 + kb*16) ^ ((m_&7)<<4);
    int boff = ((ks*4 + w)*64 + lane)*8;
    bf16x8 a0 = *(const bf16x8*)(prB0 + aoff);
    bf16x8 a1 = *(const bf16x8*)(prB1 + aoff);
    acc0 = __builtin_amdgcn_mfma_f32_16x16x32_bf16(a0, *(const bf16x8*)(xpB0 + boff), acc0, 0,0,0);
    acc1 = __builtin_amdgcn_mfma_f32_16x16x32_bf16(a1, *(const bf16x8*)(xpB1 + boff), acc1, 0,0,0);
  }
  __syncthreads();   // prB reads done; overlay xpT
  // stage xp window [2 j][3 rows][16 ci][64 f] (zero-padded rows), stride 68
  for(int idx4 = tid; idx4 < 1536; idx4 += 256){
    int jj = idx4 / 768;
    int rem = idx4 - jj*768;
    int rr_i = rem >> 8;
    int pos = rem & 255;
    int ci = pos>>4, f4 = pos&15;
    int grow = st - 1 + rr_i;
    float4 v = {0.f,0.f,0.f,0.f};
    if(grow>=0 && grow<16){
      v = *(const float4*)(xp + ((size_t)(b*16+j0+jj)*256 + grow*16 + ci)*64 + f4*4);
    }
    *(float4*)(xpT + ((jj*3+rr_i)*16+ci)*68 + f4*4) = v;
  }
  __syncthreads();
  int f = w*16 + m_;
  #pragma unroll
  for(int jj=0;jj<2;jj++){
    int j = j0+jj;
    int bj = b*16+j;
    f32x4 acc = jj ? acc1 : acc0;
    float al = fabsf(alpha[j]), be=fabsf(beta[j]), th=fabsf(theta[j]), ga=gamma_[j];
    const float* wq = cw + (j*64+f)*9;
    float w0=wq[0],w1=wq[1],w2=wq[2],w3v=wq[3],w4=wq[4],w5=wq[5],w6=wq[6],w7=wq[7],w8=wq[8];
    #pragma unroll
    for(int r=0;r<4;r++){
      int si = kb*4 + r;
      int s = st*16 + si;
      float gl = acc[r];
      float cv=0.f;
      #pragma unroll
      for(int dr=0;dr<3;dr++){
        float kw0 = dr==0?w0:(dr==1?w3v:w6);
        float kw1 = dr==0?w1:(dr==1?w4:w7);
        float kw2 = dr==0?w2:(dr==1?w5:w8);
        const float* rowp = xpT + ((jj*3+dr)*16)*68;
        if(si>0)  cv += rowp[(si-1)*68+f]*kw0;
                  cv += rowp[(si  )*68+f]*kw1;
        if(si<15) cv += rowp[(si+1)*68+f]*kw2;
      }
      float diag = xpT[((jj*3+1)*16+si)*68+f];
      size_t gi = ((size_t)bj*256+s)*64+f;
      out[gi] = be*gl + al*diag + th*cv + ga*bf2f(xarrb[gi]);
    }
  }
}

extern "C" void kernel_launch(void* const* d_in, const int* in_sizes, int n_in,
                              void* d_out, int out_size, void* d_ws, size_t ws_size,
                              hipStream_t stream) {
  const float* xin = (const float*)d_in[0];
  const float* pxp = (const float*)d_in[1];
  const float* sw  = (const float*)d_in[2];
  const float* bs  = (const float*)d_in[3];
  const float* tau = (const float*)d_in[4];
  const float* temp= (const float*)d_in[5];
  const float* om  = (const float*)d_in[6];
  const float* W2  = (const float*)d_in[7];
  const float* bp  = (const float*)d_in[8];
  const float* lnw = (const float*)d_in[9];
  const float* lnb = (const float*)d_in[10];
  const float* alpha=(const float*)d_in[11];
  const float* beta= (const float*)d_in[12];
  const float* gam = (const float*)d_in[13];
  const float* theta=(const float*)d_in[14];
  const float* cw  = (const float*)d_in[15];
  float* outp = (float*)d_out;
  float* xpo  = outp + 2097152;   // x_prime = second output

  float* ws  = (float*)d_ws;
  float* xe  = ws;                // 32768
  float* xa  = xe + 32768;        // 32768
  float* Sv  = xa + 32768;        // 32768
  float* SSv = Sv + 32768;        // 32768
  float* er2 = SSv + 32768;       // 524288
  float* mask= er2 + 524288;      // 2048
  float* ccv = mask + 2048;       // 2048
  float* Gv  = ccv + 2048;        // 4194304
  u16* xvb = (u16*)(Gv + 4194304);    // 2097152 u16 (bf16 x)
  u16* xpB = xvb + 2097152;           // 2097152 u16
  u16* w2B = xpB + 2097152;           // 65536 u16
  u16* xinb= w2B + 65536;             // 2097152 u16
  u16* phi = xinb + 2097152;          // 2097152 u16
  u16* plo = phi + 2097152;           // 2097152 u16

  kA<<<1024,256,0,stream>>>(xin,pxp,W2,xe,xa,Sv,SSv,xinb,phi,plo,w2B);
  kBE<<<1152,256,0,stream>>>(xe,sw,bs,om,xa,tau,temp,er2,mask,ccv,phi,plo,Gv);
  kD<<<dim3(8,16,16),256,0,stream>>>(xinb,er2,mask,w2B,lnw,lnb,bp,xvb,xpo,xpB);
  kF<<<dim3(8,8,16),256,0,stream>>>(Gv,ccv,Sv,SSv,xpo,xpB,cw,xvb,temp,
                                    alpha,beta,gam,theta,outp);
}